// Round 8
// baseline (1488.284 us; speedup 1.0000x reference)
//
#include <hip/hip_runtime.h>
#include <cmath>

// Volume: [B=4, C=1, D=128, H=128, W=128] fp32
#define NB 4
#define ND 128
#define NH 128
#define NW 128
#define NVOL_VOX (ND * NH * NW)    // 2097152 per volume
#define NVOX (NB * NVOL_VOX)       // 8388608 (4 volumes)

#define THREADS 256
#define TX 32                      // tile x (floats) = 8 data f4
#define TY 8                       // tile y rows
#define FSTR 13                    // uniform f4 frame stride (any works: rows-of-16 are phase-aligned)
#define ZS4 ((NH * NW) >> 2)       // 4096 f4 per z-slice

__device__ __forceinline__ float4 f4min(float4 a, float4 b) {
    return make_float4(fminf(a.x, b.x), fminf(a.y, b.y), fminf(a.z, b.z), fminf(a.w, b.w));
}
__device__ __forceinline__ float4 f4max(float4 a, float4 b) {
    return make_float4(fmaxf(a.x, b.x), fmaxf(a.y, b.y), fmaxf(a.z, b.z), fmaxf(a.w, b.w));
}
__device__ __forceinline__ float4 f4relu_sub(float4 a, float4 b) {
    return make_float4(fmaxf(a.x - b.x, 0.f), fmaxf(a.y - b.y, 0.f),
                       fmaxf(a.z - b.z, 0.f), fmaxf(a.w - b.w, 0.f));
}
__device__ __forceinline__ float4 f4winmin(float4 lf, float4 cc, float4 rt) {
    float4 o;
    o.x = fminf(fminf(lf.w, cc.x), cc.y);
    o.y = fminf(fminf(cc.x, cc.y), cc.z);
    o.z = fminf(fminf(cc.y, cc.z), cc.w);
    o.w = fminf(fminf(cc.z, cc.w), rt.x);
    return o;
}
__device__ __forceinline__ float4 f4winmax(float4 lf, float4 cc, float4 rt) {
    float4 o;
    o.x = fmaxf(fmaxf(lf.w, cc.x), cc.y);
    o.y = fmaxf(fmaxf(cc.x, cc.y), cc.z);
    o.z = fmaxf(fmaxf(cc.y, cc.z), cc.w);
    o.w = fmaxf(fmaxf(cc.z, cc.w), rt.x);
    return o;
}

__device__ __forceinline__ float block_reduce(float v, float* sbuf) {
    for (int off = 32; off > 0; off >>= 1) v += __shfl_down(v, off, 64);
    int lane = threadIdx.x & 63;
    int wid  = threadIdx.x >> 6;
    if (lane == 0) sbuf[wid] = v;
    __syncthreads();
    float r = 0.f;
    if (wid == 0) {
        r = (lane < (int)(blockDim.x >> 6)) ? sbuf[lane] : 0.f;
        for (int off = 8; off > 0; off >>= 1) r += __shfl_down(r, off, 64);
    }
    __syncthreads();
    return r;
}

// ---------------------------------------------------------------------------
// sigmoid + dice partials
// ---------------------------------------------------------------------------
#define SIG_BLOCKS 1024
__global__ void sigmoid_reduce_kernel(const float4* __restrict__ logits,
                                      const float4* __restrict__ yt,
                                      float4* __restrict__ yp,
                                      float* __restrict__ part) {
    __shared__ float sbuf[THREADS / 64];
    const int n4 = NVOX / 4;
    float sp = 0.f, st = 0.f, stp = 0.f;
    for (int i = blockIdx.x * blockDim.x + threadIdx.x; i < n4;
         i += gridDim.x * blockDim.x) {
        float4 l = logits[i];
        float4 t = yt[i];
        float4 p;
        p.x = 1.f / (1.f + expf(-l.x));
        p.y = 1.f / (1.f + expf(-l.y));
        p.z = 1.f / (1.f + expf(-l.z));
        p.w = 1.f / (1.f + expf(-l.w));
        yp[i] = p;
        sp  += p.x + p.y + p.z + p.w;
        st  += t.x + t.y + t.z + t.w;
        stp += t.x * p.x + t.y * p.y + t.z * p.z + t.w * p.w;
    }
    float a = block_reduce(sp, sbuf);
    float b = block_reduce(st, sbuf);
    float c = block_reduce(stp, sbuf);
    if (threadIdx.x == 0) {
        part[blockIdx.x]        = a;
        part[1024 + blockIdx.x] = b;
        part[2048 + blockIdx.x] = c;
    }
}

// ---------------------------------------------------------------------------
// Init step: skel = relu(src - dilate(erode(src)))
// Rows-of-16 mapping (phase-aligned, conflict-free), 2-slot frames, 1 barrier.
// Rows: src 14 (y halo 3), e1 12 (halo 2), rx 10 (halo 1), center 8.
// ---------------------------------------------------------------------------
__global__ __launch_bounds__(256, 4)
void init_step_kernel(const float* __restrict__ srcA, const float* __restrict__ srcB,
                      float* __restrict__ skel, int zchunks) {
    __shared__ float4 srcS[2][14 * FSTR];
    __shared__ float4 e1S [2][12 * FSTR];
    __shared__ float4 rxS [2][10 * FSTR];

    const float4 INF4  = make_float4(INFINITY, INFINITY, INFINITY, INFINITY);
    const float4 MINF4 = make_float4(-INFINITY, -INFINITY, -INFINITY, -INFINITY);

    const int zlen  = ND / zchunks;
    const int v     = blockIdx.z / zchunks;
    const int chunk = blockIdx.z - v * zchunks;
    const int z0    = chunk * zlen;
    const int tx0   = blockIdx.x * TX;
    const int ty0   = blockIdx.y * TY;
    const int tid   = threadIdx.x;

    const float* src = srcB ? (v < 4 ? srcA + (size_t)v * NVOL_VOX
                                     : srcB + (size_t)(v - 4) * NVOL_VOX)
                            : srcA + (size_t)v * NVOL_VOX;
    const float4* src4 = (const float4*)src;
    float4* skl4 = (float4*)(skel + (size_t)v * NVOL_VOX);

    const int fy = tid >> 4;          // 0..15 (src uses 0..13)
    const int qx = tid & 15;          // active 0..9
    const bool tOK = qx < 10 && fy < 14;
    const bool aE1 = qx < 10 && fy >= 1 && fy <= 12;
    const bool aRx = fy >= 2 && fy <= 11 && qx >= 1 && qx <= 8;
    const bool aC  = fy >= 3 && fy <= 10 && qx >= 1 && qx <= 8;
    const int gy  = ty0 + fy - 3;
    const int gx4 = tx0 + (qx - 1) * 4;
    const bool gOK = tOK && (unsigned)gy < NH && (unsigned)gx4 < NW;
    const int colBase = gOK ? ((gy * NW + gx4) >> 2) : 0;
    const int iSrc = fy * FSTR + qx + 1;
    const int iE1  = (fy - 1) * FSTR + qx + 1;
    const int iRx  = (fy - 2) * FSTR + (qx - 1);

    // guards: cols 0 and 11 of the min-frames, both slots
    for (int l = tid; l < 2 * 2 * 14; l += THREADS)
        srcS[l & 1][(l >> 2) * FSTR + ((l >> 1) & 1) * 11] = INF4;
    for (int l = tid; l < 2 * 2 * 12; l += THREADS)
        e1S[l & 1][(l >> 2) * FSTR + ((l >> 1) & 1) * 11] = INF4;
    __syncthreads();

    float4 srcF[6], e1F[2], rxF[2], mxyF[3];
#pragma unroll
    for (int i = 0; i < 6; ++i) srcF[i] = INF4;
    e1F[0] = e1F[1] = INF4;
    rxF[0] = rxF[1] = MINF4;
    mxyF[0] = mxyF[1] = mxyF[2] = MINF4;

    const int NSTEP = zlen + 8;
    for (int sb = 0; sb < NSTEP; sb += 6) {
#pragma unroll
        for (int u = 0; u < 6; ++u) {
            const int zL = z0 - 3 + (sb + u);
            const int sl  = u & 1;
            const int slp = sl ^ 1;

            {   // L(zL)
                float4 vv = INF4;
                if ((unsigned)zL < ND && zL < z0 + zlen + 3 && gOK)
                    vv = src4[zL * ZS4 + colBase];
                srcF[u % 6] = vv;
                if (tOK) srcS[sl][iSrc] = vv;
            }
            {   // e1(zL-1): srcS[slp] holds src(zL-1)
                const int z = zL - 1;
                float4 vv = INF4;
                if (aE1 && (unsigned)z < ND) {
                    const float4* S = srcS[slp];
                    float4 xm = f4winmin(S[iSrc - 1], srcF[(u + 5) % 6], S[iSrc + 1]);
                    vv = f4min(f4min(xm, S[iSrc - FSTR]),
                               f4min(S[iSrc + FSTR],
                                     f4min(srcF[(u + 4) % 6], srcF[u % 6])));
                }
                e1F[u % 2] = vv;
                if (aE1) e1S[sl][iE1] = vv;
            }
            {   // rx(zL-2) = max3x(e1(zL-2)); mxy(zL-3) = max3y(rx(zL-3))
                float4 rxv = MINF4;
                if (aRx) {
                    const float4* S = e1S[slp];
                    rxv = f4winmax(S[iE1 - 1], e1F[(u + 1) % 2], S[iE1 + 1]);
                    rxS[sl][iRx] = rxv;
                }
                float4 m = MINF4;
                if (aC)
                    m = f4max(f4max(rxF[(u + 1) % 2], rxS[slp][iRx - FSTR]),
                              rxS[slp][iRx + FSTR]);
                rxF[u % 2] = rxv;
                mxyF[u % 3] = m;
            }
            {   // OUT(zL-4): skel = relu(src - dil)
                const int z = zL - 4;
                if (aC && z >= z0 && z < z0 + zlen) {
                    float4 dil = f4max(f4max(mxyF[0], mxyF[1]), mxyF[2]);
                    skl4[z * ZS4 + colBase] = f4relu_sub(srcF[(u + 2) % 6], dil);
                }
            }
            __syncthreads();
        }
    }
}

// ---------------------------------------------------------------------------
// Fused PAIR of skeleton iterations, rows-of-16, 2-slot frames, 1 barrier.
//   E1 = erode(src); E2 = erode(E1) [img out]; E3 = erode(E2)
//   dA = relu(E1 - dilate(E2));  dB = relu(E2 - dilate(E3))
//   s1 = s + relu(dA - s*dA); s2 = s1 + relu(dB - s1*dB)
// Rows: src 16 (halo 4), e1 14, e2 12, e3 10, rx 10, center 8.
// ---------------------------------------------------------------------------
template <int RED>
__global__ __launch_bounds__(256, 4)
void skel_pair_kernel(const float* __restrict__ srcA, const float* __restrict__ srcB,
                      float* __restrict__ imgOut, float* __restrict__ skel,
                      int zchunks,
                      const float* __restrict__ othA, const float* __restrict__ othB,
                      float* __restrict__ part, int offBase) {
    __shared__ float4 srcS[2][16 * FSTR];
    __shared__ float4 e1S [2][14 * FSTR];
    __shared__ float4 e2S [2][12 * FSTR];
    __shared__ float4 e3S [2][10 * FSTR];
    __shared__ float4 rxAS[2][10 * FSTR];
    __shared__ float4 rxBS[2][10 * FSTR];

    const float4 INF4  = make_float4(INFINITY, INFINITY, INFINITY, INFINITY);
    const float4 MINF4 = make_float4(-INFINITY, -INFINITY, -INFINITY, -INFINITY);

    const int zlen  = ND / zchunks;
    const int v     = blockIdx.z / zchunks;
    const int chunk = blockIdx.z - v * zchunks;
    const int z0    = chunk * zlen;
    const int tx0   = blockIdx.x * TX;
    const int ty0   = blockIdx.y * TY;
    const int tid   = threadIdx.x;

    const float* src = srcB ? (v < 4 ? srcA + (size_t)v * NVOL_VOX
                                     : srcB + (size_t)(v - 4) * NVOL_VOX)
                            : srcA + (size_t)v * NVOL_VOX;
    const float4* src4 = (const float4*)src;
    float4* img4 = imgOut ? (float4*)(imgOut + (size_t)v * NVOL_VOX) : nullptr;
    float4* skl4 = (float4*)(skel + (size_t)v * NVOL_VOX);
    const float4* oth4 = nullptr;
    if (RED) {
        const float* oth = othB ? (v < 4 ? othA + (size_t)v * NVOL_VOX
                                         : othB + (size_t)(v - 4) * NVOL_VOX)
                                : othA + (size_t)v * NVOL_VOX;
        oth4 = (const float4*)oth;
    }

    const int fy = tid >> 4;          // 0..15
    const int qx = tid & 15;          // active 0..9
    const bool tOK = qx < 10;
    const bool aE1 = tOK && fy >= 1 && fy <= 14;
    const bool aE2 = tOK && fy >= 2 && fy <= 13;
    const bool aE3 = tOK && fy >= 3 && fy <= 12;
    const bool aRx = fy >= 3 && fy <= 12 && qx >= 1 && qx <= 8;
    const bool aC  = fy >= 4 && fy <= 11 && qx >= 1 && qx <= 8;
    const int gy  = ty0 + fy - 4;
    const int gx4 = tx0 + (qx - 1) * 4;
    const bool gOK = tOK && (unsigned)gy < NH && (unsigned)gx4 < NW;
    const int colBase = gOK ? ((gy * NW + gx4) >> 2) : 0;
    const int iSrc = fy * FSTR + qx + 1;
    const int iE1  = (fy - 1) * FSTR + qx + 1;
    const int iE2  = (fy - 2) * FSTR + qx + 1;
    const int iE3  = (fy - 3) * FSTR + qx + 1;
    const int iRx  = (fy - 3) * FSTR + (qx - 1);

    // guards: cols 0 and 11, both slots, all min-frames
    for (int l = tid; l < 2 * 2 * 16; l += THREADS)
        srcS[l & 1][(l >> 2) * FSTR + ((l >> 1) & 1) * 11] = INF4;
    for (int l = tid; l < 2 * 2 * 14; l += THREADS)
        e1S[l & 1][(l >> 2) * FSTR + ((l >> 1) & 1) * 11] = INF4;
    for (int l = tid; l < 2 * 2 * 12; l += THREADS)
        e2S[l & 1][(l >> 2) * FSTR + ((l >> 1) & 1) * 11] = INF4;
    for (int l = tid; l < 2 * 2 * 10; l += THREADS)
        e3S[l & 1][(l >> 2) * FSTR + ((l >> 1) & 1) * 11] = INF4;
    __syncthreads();

    float4 srcF[3], e1F[6], e2F[6], e3F[2], rxAF[2], rxBF[2], mxyAF[3], mxyBF[3], dAF[2];
#pragma unroll
    for (int i = 0; i < 3; ++i) srcF[i] = INF4;
#pragma unroll
    for (int i = 0; i < 6; ++i) { e1F[i] = INF4; e2F[i] = INF4; }
    e3F[0] = e3F[1] = INF4;
    rxAF[0] = rxAF[1] = MINF4;
    rxBF[0] = rxBF[1] = MINF4;
    mxyAF[0] = mxyAF[1] = mxyAF[2] = MINF4;
    mxyBF[0] = mxyBF[1] = mxyBF[2] = MINF4;
    dAF[0] = dAF[1] = make_float4(0.f, 0.f, 0.f, 0.f);

    float accS = 0.f, accSO = 0.f;
    const int NSTEP = zlen + 10;

    for (int sb = 0; sb < NSTEP; sb += 6) {
#pragma unroll
        for (int u = 0; u < 6; ++u) {
            const int zL = z0 - 4 + (sb + u);
            const int sl  = u & 1;
            const int slp = sl ^ 1;

            {   // L(zL)
                float4 vv = INF4;
                if ((unsigned)zL < ND && zL < z0 + zlen + 4 && gOK)
                    vv = src4[zL * ZS4 + colBase];
                srcF[u % 3] = vv;
                if (tOK) srcS[sl][iSrc] = vv;
            }
            {   // E1(zL-1)
                const int z = zL - 1;
                float4 vv = INF4;
                if (aE1 && (unsigned)z < ND) {
                    const float4* S = srcS[slp];
                    float4 xm = f4winmin(S[iSrc - 1], srcF[(u + 2) % 3], S[iSrc + 1]);
                    vv = f4min(f4min(xm, S[iSrc - FSTR]),
                               f4min(S[iSrc + FSTR],
                                     f4min(srcF[(u + 1) % 3], srcF[u % 3])));
                }
                e1F[u % 6] = vv;
                if (aE1) e1S[sl][iE1] = vv;
            }
            {   // E2(zL-2) — img output
                const int z = zL - 2;
                float4 vv = INF4;
                if (aE2) {
                    const float4* S = e1S[slp];
                    float4 xm = f4winmin(S[iE1 - 1], e1F[(u + 5) % 6], S[iE1 + 1]);
                    vv = f4min(f4min(xm, S[iE1 - FSTR]),
                               f4min(S[iE1 + FSTR],
                                     f4min(e1F[(u + 4) % 6], e1F[u % 6])));
                    e2S[sl][iE2] = vv;
                    if (img4 && aC && z >= z0 && z < z0 + zlen)
                        img4[z * ZS4 + colBase] = vv;
                }
                e2F[u % 6] = vv;
            }
            {   // E3(zL-3)
                float4 vv = INF4;
                if (aE3) {
                    const float4* S = e2S[slp];
                    float4 xm = f4winmin(S[iE2 - 1], e2F[(u + 5) % 6], S[iE2 + 1]);
                    vv = f4min(f4min(xm, S[iE2 - FSTR]),
                               f4min(S[iE2 + FSTR],
                                     f4min(e2F[(u + 4) % 6], e2F[u % 6])));
                    e3S[sl][iE3] = vv;
                }
                e3F[u % 2] = vv;
            }
            {   // rxA(zL-3) from e2S[slp]; rxB(zL-4) from e3S[slp]
                float4 ra = MINF4, rb = MINF4;
                if (aRx) {
                    const float4* SA = e2S[slp];
                    const float4* SB = e3S[slp];
                    ra = f4winmax(SA[iE2 - 1], e2F[(u + 5) % 6], SA[iE2 + 1]);
                    rb = f4winmax(SB[iE3 - 1], e3F[(u + 1) % 2], SB[iE3 + 1]);
                    rxAS[sl][iRx] = ra;
                    rxBS[sl][iRx] = rb;
                }
                // mxyA(zL-4), mxyB(zL-5)
                float4 mA = MINF4, mB = MINF4;
                if (aC) {
                    mA = f4max(f4max(rxAF[(u + 1) % 2], rxAS[slp][iRx - FSTR]),
                               rxAS[slp][iRx + FSTR]);
                    mB = f4max(f4max(rxBF[(u + 1) % 2], rxBS[slp][iRx - FSTR]),
                               rxBS[slp][iRx + FSTR]);
                }
                rxAF[u % 2] = ra;
                rxBF[u % 2] = rb;
                mxyAF[u % 3] = mA;
                mxyBF[u % 3] = mB;
            }
            {   // dA(zL-5) = relu(E1(zL-5) - dilA)
                float4 dilA = f4max(f4max(mxyAF[0], mxyAF[1]), mxyAF[2]);
                dAF[u % 2] = f4relu_sub(e1F[(u + 2) % 6], dilA);
            }
            {   // OUT(zL-6): apply dA then dB
                const int z = zL - 6;
                if (aC && z >= z0 && z < z0 + zlen) {
                    float4 dilB = f4max(f4max(mxyBF[0], mxyBF[1]), mxyBF[2]);
                    float4 dB = f4relu_sub(e2F[(u + 2) % 6], dilB);
                    float4 da = dAF[(u + 1) % 2];
                    int gi = z * ZS4 + colBase;
                    float4 sv = skl4[gi];
                    float4 s1, s2;
                    s1.x = sv.x + fmaxf(da.x - sv.x * da.x, 0.f);
                    s1.y = sv.y + fmaxf(da.y - sv.y * da.y, 0.f);
                    s1.z = sv.z + fmaxf(da.z - sv.z * da.z, 0.f);
                    s1.w = sv.w + fmaxf(da.w - sv.w * da.w, 0.f);
                    s2.x = s1.x + fmaxf(dB.x - s1.x * dB.x, 0.f);
                    s2.y = s1.y + fmaxf(dB.y - s1.y * dB.y, 0.f);
                    s2.z = s1.z + fmaxf(dB.z - s1.z * dB.z, 0.f);
                    s2.w = s1.w + fmaxf(dB.w - s1.w * dB.w, 0.f);
                    skl4[gi] = s2;
                    if (RED) {
                        accS += s2.x + s2.y + s2.z + s2.w;
                        float4 o = oth4[gi];
                        accSO += s2.x * o.x + s2.y * o.y + s2.z * o.z + s2.w * o.w;
                    }
                }
            }
            __syncthreads();
        }
    }

    if (RED) {
        float* sbuf = (float*)srcS;
        float r1 = block_reduce(accS, sbuf);
        float r2 = block_reduce(accSO, sbuf);
        if (tid == 0) {
            int halfSel = (othB && v >= 4) ? 1 : 0;
            int A = (offBase + 2 * halfSel) * 1024;
            int zslot = chunk + zchunks * (v & 3);
            int bid = blockIdx.x + 4 * (blockIdx.y + 16 * zslot);
            part[A + bid] = r1;
            part[A + 1024 + bid] = r2;
        }
    }
}

// ---------------------------------------------------------------------------
// finalize: sum 7 partial arrays (1024 each) and compute the loss scalar
// ---------------------------------------------------------------------------
__global__ void finalize_kernel(const float* __restrict__ part, float* __restrict__ out) {
    __shared__ float sbuf[THREADS / 64];
    float s[7];
#pragma unroll
    for (int k = 0; k < 7; ++k) {
        float local = 0.f;
        for (int i = threadIdx.x; i < 1024; i += THREADS) local += part[k * 1024 + i];
        s[k] = block_reduce(local, sbuf);
    }
    if (threadIdx.x == 0) {
        const float smooth = 1.0f;
        const float alpha = 0.3f;
        float dice = 1.f - (2.f * s[2] + smooth) / (s[1] + s[0] + smooth);
        float tprec = (s[4] + smooth) / (s[3] + smooth);
        float tsens = (s[6] + smooth) / (s[5] + smooth);
        float cl = 1.f - 2.f * (tprec * tsens) / (tprec + tsens);
        out[0] = (1.f - alpha) * dice + alpha * cl;
    }
}

// ---------------------------------------------------------------------------
extern "C" void kernel_launch(void* const* d_in, const int* in_sizes, int n_in,
                              void* d_out, int out_size, void* d_ws, size_t ws_size,
                              hipStream_t stream) {
    const float* y_pred = (const float*)d_in[0];
    const float* y_true = (const float*)d_in[1];
    float* out = (float*)d_out;

    char* ws = (char*)d_ws;
    float* part = (float*)ws;                 // 7 * 1024 floats
    float* yp = (float*)(ws + 32768);
    const size_t NB4 = (size_t)NVOX;
    const size_t need_batched = 32768 + 7 * NB4 * sizeof(float);

    hipMemsetAsync(part, 0, 7 * 1024 * sizeof(float), stream);
    sigmoid_reduce_kernel<<<SIG_BLOCKS, THREADS, 0, stream>>>(
        (const float4*)y_pred, (const float4*)y_true, (float4*)yp, part);

    if (ws_size >= need_batched) {
        // batched: both skeletons (8 volumes) per dispatch
        float* ping = yp + NB4;          // 8-vol
        float* pong = ping + 2 * NB4;    // 8-vol
        float* S    = pong + 2 * NB4;    // 8-vol
        const int zc = 2;                // zlen 64
        dim3 grid(NW / TX, NH / TY, zc * 8);   // 4 x 16 x 16 = 1024 blocks = 4/CU

        init_step_kernel<<<grid, THREADS, 0, stream>>>(yp, y_true, S, zc);

        float* bufs[2] = {ping, pong};
        for (int i = 0; i < 8; ++i) {
            const float* sA = (i == 0) ? yp : bufs[(i + 1) & 1];
            const float* sB = (i == 0) ? y_true : nullptr;
            float* oimg = (i < 7) ? bufs[i & 1] : nullptr;   // last pair: img dead
            if (i < 7)
                skel_pair_kernel<0><<<grid, THREADS, 0, stream>>>(
                    sA, sB, oimg, S, zc, nullptr, nullptr, nullptr, 0);
            else
                skel_pair_kernel<1><<<grid, THREADS, 0, stream>>>(
                    sA, sB, oimg, S, zc, y_true, yp, part, 3);
        }
    } else {
        // sequential fallback: one skeleton stream (4 vols) at a time
        float* ping = yp + NB4;
        float* pong = ping + NB4;
        float* Sp   = pong + NB4;
        float* St   = Sp + NB4;
        const int zc = 4;                // zlen 32
        dim3 grid(NW / TX, NH / TY, zc * 4);   // 4 x 16 x 16 = 1024 blocks

        auto run = [&](const float* x, float* S, const float* other, int offBase) {
            init_step_kernel<<<grid, THREADS, 0, stream>>>(x, nullptr, S, zc);
            float* bufs[2] = {ping, pong};
            for (int i = 0; i < 8; ++i) {
                const float* sA = (i == 0) ? x : bufs[(i + 1) & 1];
                float* oimg = (i < 7) ? bufs[i & 1] : nullptr;
                if (i < 7)
                    skel_pair_kernel<0><<<grid, THREADS, 0, stream>>>(
                        sA, nullptr, oimg, S, zc, nullptr, nullptr, nullptr, 0);
                else
                    skel_pair_kernel<1><<<grid, THREADS, 0, stream>>>(
                        sA, nullptr, oimg, S, zc, other, nullptr, part, offBase);
            }
        };
        run(yp, Sp, y_true, 3);
        run(y_true, St, yp, 5);
    }

    finalize_kernel<<<1, THREADS, 0, stream>>>(part, out);
}

// Round 9
// 1043.692 us; speedup vs baseline: 1.4260x; 1.4260x over previous
//
#include <hip/hip_runtime.h>
#include <cmath>

// Volume: [B=4, C=1, D=128, H=128, W=128] fp32
#define NB 4
#define ND 128
#define NH 128
#define NW 128
#define NVOL_VOX (ND * NH * NW)    // 2097152 per volume
#define NVOX (NB * NVOL_VOX)       // 8388608 (4 volumes)

#define THREADS 256
#define TX 32
#define TY 16
#define SSTR 13
#define RSTR 9
#define ZS4 ((NH * NW) >> 2)       // 4096 f4 per z-slice

__device__ __forceinline__ float4 f4min(float4 a, float4 b) {
    return make_float4(fminf(a.x, b.x), fminf(a.y, b.y), fminf(a.z, b.z), fminf(a.w, b.w));
}
__device__ __forceinline__ float4 f4max(float4 a, float4 b) {
    return make_float4(fmaxf(a.x, b.x), fmaxf(a.y, b.y), fmaxf(a.z, b.z), fmaxf(a.w, b.w));
}
__device__ __forceinline__ float4 f4relu_sub(float4 a, float4 b) {
    return make_float4(fmaxf(a.x - b.x, 0.f), fmaxf(a.y - b.y, 0.f),
                       fmaxf(a.z - b.z, 0.f), fmaxf(a.w - b.w, 0.f));
}
__device__ __forceinline__ float4 f4winmin(float4 lf, float4 cc, float4 rt) {
    float4 o;
    o.x = fminf(fminf(lf.w, cc.x), cc.y);
    o.y = fminf(fminf(cc.x, cc.y), cc.z);
    o.z = fminf(fminf(cc.y, cc.z), cc.w);
    o.w = fminf(fminf(cc.z, cc.w), rt.x);
    return o;
}
__device__ __forceinline__ float4 f4winmax(float4 lf, float4 cc, float4 rt) {
    float4 o;
    o.x = fmaxf(fmaxf(lf.w, cc.x), cc.y);
    o.y = fmaxf(fmaxf(cc.x, cc.y), cc.z);
    o.z = fmaxf(fmaxf(cc.y, cc.z), cc.w);
    o.w = fmaxf(fmaxf(cc.z, cc.w), rt.x);
    return o;
}

__device__ __forceinline__ float block_reduce(float v, float* sbuf) {
    for (int off = 32; off > 0; off >>= 1) v += __shfl_down(v, off, 64);
    int lane = threadIdx.x & 63;
    int wid  = threadIdx.x >> 6;
    if (lane == 0) sbuf[wid] = v;
    __syncthreads();
    float r = 0.f;
    if (wid == 0) {
        r = (lane < (int)(blockDim.x >> 6)) ? sbuf[lane] : 0.f;
        for (int off = 8; off > 0; off >>= 1) r += __shfl_down(r, off, 64);
    }
    __syncthreads();
    return r;
}

// ---------------------------------------------------------------------------
// sigmoid + dice partials
// ---------------------------------------------------------------------------
#define SIG_BLOCKS 1024
__global__ void sigmoid_reduce_kernel(const float4* __restrict__ logits,
                                      const float4* __restrict__ yt,
                                      float4* __restrict__ yp,
                                      float* __restrict__ part) {
    __shared__ float sbuf[THREADS / 64];
    const int n4 = NVOX / 4;
    float sp = 0.f, st = 0.f, stp = 0.f;
    for (int i = blockIdx.x * blockDim.x + threadIdx.x; i < n4;
         i += gridDim.x * blockDim.x) {
        float4 l = logits[i];
        float4 t = yt[i];
        float4 p;
        p.x = 1.f / (1.f + expf(-l.x));
        p.y = 1.f / (1.f + expf(-l.y));
        p.z = 1.f / (1.f + expf(-l.z));
        p.w = 1.f / (1.f + expf(-l.w));
        yp[i] = p;
        sp  += p.x + p.y + p.z + p.w;
        st  += t.x + t.y + t.z + t.w;
        stp += t.x * p.x + t.y * p.y + t.z * p.z + t.w * p.w;
    }
    float a = block_reduce(sp, sbuf);
    float b = block_reduce(st, sbuf);
    float c = block_reduce(stp, sbuf);
    if (threadIdx.x == 0) {
        part[blockIdx.x]        = a;
        part[1024 + blockIdx.x] = b;
        part[2048 + blockIdx.x] = c;
    }
}

// ---------------------------------------------------------------------------
// Init step (round-6 structure): skel = relu(src - dilate(erode(src)))
// ---------------------------------------------------------------------------
__global__ __launch_bounds__(256, 4)
void init_step_kernel(const float* __restrict__ srcA, const float* __restrict__ srcB,
                      float* __restrict__ skel, int zchunks) {
    __shared__ float4 srcS[2][22 * SSTR];
    __shared__ float4 e1S [2][20 * SSTR];
    __shared__ float4 rxS [2][18 * RSTR];

    const float4 INF4  = make_float4(INFINITY, INFINITY, INFINITY, INFINITY);
    const float4 MINF4 = make_float4(-INFINITY, -INFINITY, -INFINITY, -INFINITY);

    const int zlen  = ND / zchunks;
    const int v     = blockIdx.z / zchunks;
    const int chunk = blockIdx.z - v * zchunks;
    const int z0    = chunk * zlen;
    const int tx0   = blockIdx.x * TX;
    const int ty0   = blockIdx.y * TY;
    const int tid   = threadIdx.x;

    const float* src = srcB ? (v < 4 ? srcA + (size_t)v * NVOL_VOX
                                     : srcB + (size_t)(v - 4) * NVOL_VOX)
                            : srcA + (size_t)v * NVOL_VOX;
    const float4* src4 = (const float4*)src;
    float4* skl4 = (float4*)(skel + (size_t)v * NVOL_VOX);

    const int fy = tid / 10, qx = tid - (tid / 10) * 10;
    const bool tOK = tid < 220;
    const bool aE1 = tOK && fy >= 1 && fy < 21;
    const bool aRx = tOK && fy >= 2 && fy < 20 && qx >= 1 && qx < 9;
    const bool aC  = tOK && fy >= 3 && fy < 19 && qx >= 1 && qx < 9;
    const int gy = ty0 + fy - 3;
    const int gx4 = tx0 + (qx - 1) * 4;
    const bool gOK = tOK && (unsigned)gy < NH && (unsigned)gx4 < NW;
    const int colBase = gOK ? ((gy * NW + gx4) >> 2) : 0;
    const int iSrc = fy * SSTR + qx + 1;
    const int iE1  = (fy - 1) * SSTR + qx + 1;
    const int iRx  = (fy - 2) * RSTR + (qx - 1);

    for (int l = tid; l < 2 * 22 * 2; l += THREADS)
        srcS[l & 1][(l >> 2) * SSTR + ((l >> 1) & 1) * 11] = INF4;
    for (int l = tid; l < 2 * 20 * 2; l += THREADS)
        e1S[l & 1][(l >> 2) * SSTR + ((l >> 1) & 1) * 11] = INF4;
    __syncthreads();

    float4 srcF[6], e1F[2], rxF[2], mxyF[3];
#pragma unroll
    for (int i = 0; i < 6; ++i) srcF[i] = INF4;
    e1F[0] = e1F[1] = INF4;
    rxF[0] = rxF[1] = MINF4;
    mxyF[0] = mxyF[1] = mxyF[2] = MINF4;

    const int NSTEP = zlen + 8;
    for (int sb = 0; sb < NSTEP; sb += 6) {
#pragma unroll
        for (int u = 0; u < 6; ++u) {
            const int zL = z0 - 3 + (sb + u);
            const int sl  = u & 1;
            const int slp = sl ^ 1;

            {   // L(zL)
                float4 vv = INF4;
                if ((unsigned)zL < ND && zL < z0 + zlen + 3 && gOK)
                    vv = src4[zL * ZS4 + colBase];
                srcF[u % 6] = vv;
                if (tOK) srcS[sl][iSrc] = vv;
            }
            {   // e1(zL-1)
                const int z = zL - 1;
                float4 vv = INF4;
                if (aE1 && (unsigned)z < ND) {
                    const float4* S = srcS[slp];
                    float4 xm = f4winmin(S[iSrc - 1], srcF[(u + 5) % 6], S[iSrc + 1]);
                    vv = f4min(f4min(xm, S[iSrc - SSTR]),
                               f4min(S[iSrc + SSTR],
                                     f4min(srcF[(u + 4) % 6], srcF[u % 6])));
                }
                e1F[u % 2] = vv;
                if (aE1) e1S[sl][iE1] = vv;
            }
            {   // rx(zL-2) = max3x(e1(zL-2)); mxy(zL-3) = max3y(rx(zL-3))
                float4 rxv = MINF4;
                if (aRx) {
                    const float4* S = e1S[slp];
                    rxv = f4winmax(S[iE1 - 1], e1F[(u + 1) % 2], S[iE1 + 1]);
                    rxS[sl][iRx] = rxv;
                }
                float4 m = MINF4;
                if (aC)
                    m = f4max(f4max(rxF[(u + 1) % 2], rxS[slp][iRx - RSTR]),
                              rxS[slp][iRx + RSTR]);
                rxF[u % 2] = rxv;
                mxyF[u % 3] = m;
            }
            {   // OUT(zL-4)
                const int z = zL - 4;
                if (aC && z >= z0 && z < z0 + zlen) {
                    float4 dil = f4max(f4max(mxyF[0], mxyF[1]), mxyF[2]);
                    skl4[z * ZS4 + colBase] = f4relu_sub(srcF[(u + 2) % 6], dil);
                }
            }
            __syncthreads();
        }
    }
}

// ---------------------------------------------------------------------------
// Fused PAIR of skeleton iterations (round-6 structure + skel/oth prefetch).
//   E1 = erode(src); E2 = erode(E1) [img out]; E3 = erode(E2)
//   dA = relu(E1 - dilate(E2));  dB = relu(E2 - dilate(E3))
//   s1 = s + relu(dA - s*dA); s2 = s1 + relu(dB - s1*dB)
// skel/oth for OUT(z) are prefetched 3 z-steps ahead into register FIFOs.
// ---------------------------------------------------------------------------
template <int RED>
__global__ __launch_bounds__(256, 2)
void skel_pair_kernel(const float* __restrict__ srcA, const float* __restrict__ srcB,
                      float* __restrict__ imgOut, float* __restrict__ skel,
                      int zchunks,
                      const float* __restrict__ othA, const float* __restrict__ othB,
                      float* __restrict__ part, int offBase) {
    __shared__ float4 srcS[2][24 * SSTR];
    __shared__ float4 e1S [2][22 * SSTR];
    __shared__ float4 e2S [2][20 * SSTR];
    __shared__ float4 e3S [2][18 * SSTR];
    __shared__ float4 rxAS[2][18 * RSTR];
    __shared__ float4 rxBS[2][18 * RSTR];

    const float4 INF4  = make_float4(INFINITY, INFINITY, INFINITY, INFINITY);
    const float4 MINF4 = make_float4(-INFINITY, -INFINITY, -INFINITY, -INFINITY);
    const float4 ZERO4 = make_float4(0.f, 0.f, 0.f, 0.f);

    const int zlen  = ND / zchunks;
    const int v     = blockIdx.z / zchunks;
    const int chunk = blockIdx.z - v * zchunks;
    const int z0    = chunk * zlen;
    const int tx0   = blockIdx.x * TX;
    const int ty0   = blockIdx.y * TY;
    const int tid   = threadIdx.x;

    const float* src = srcB ? (v < 4 ? srcA + (size_t)v * NVOL_VOX
                                     : srcB + (size_t)(v - 4) * NVOL_VOX)
                            : srcA + (size_t)v * NVOL_VOX;
    const float4* src4 = (const float4*)src;
    float4* img4 = imgOut ? (float4*)(imgOut + (size_t)v * NVOL_VOX) : nullptr;
    float4* skl4 = (float4*)(skel + (size_t)v * NVOL_VOX);
    const float4* oth4 = nullptr;
    if (RED) {
        const float* oth = othB ? (v < 4 ? othA + (size_t)v * NVOL_VOX
                                         : othB + (size_t)(v - 4) * NVOL_VOX)
                                : othA + (size_t)v * NVOL_VOX;
        oth4 = (const float4*)oth;
    }

    const int fy = tid / 10, qx = tid - (tid / 10) * 10;   // rows 0..23
    const bool tOK = tid < 240;
    const bool aE1 = tOK && fy >= 1 && fy < 23;
    const bool aE2 = tOK && fy >= 2 && fy < 22;
    const bool aE3 = tOK && fy >= 3 && fy < 21;
    const bool aRx = aE3 && qx >= 1 && qx < 9;
    const bool aC  = tOK && fy >= 4 && fy < 20 && qx >= 1 && qx < 9;
    const int gy = ty0 + fy - 4;
    const int gx4 = tx0 + (qx - 1) * 4;
    const bool gOK = tOK && (unsigned)gy < NH && (unsigned)gx4 < NW;
    const int colBase = gOK ? ((gy * NW + gx4) >> 2) : 0;
    const int iSrc = fy * SSTR + qx + 1;
    const int iE1  = (fy - 1) * SSTR + qx + 1;
    const int iE2  = (fy - 2) * SSTR + qx + 1;
    const int iE3  = (fy - 3) * SSTR + qx + 1;
    const int iRx  = (fy - 3) * RSTR + (qx - 1);

    for (int l = tid; l < 2 * 24 * 2; l += THREADS)
        srcS[l & 1][(l >> 2) * SSTR + ((l >> 1) & 1) * 11] = INF4;
    for (int l = tid; l < 2 * 22 * 2; l += THREADS)
        e1S[l & 1][(l >> 2) * SSTR + ((l >> 1) & 1) * 11] = INF4;
    for (int l = tid; l < 2 * 20 * 2; l += THREADS)
        e2S[l & 1][(l >> 2) * SSTR + ((l >> 1) & 1) * 11] = INF4;
    for (int l = tid; l < 2 * 18 * 2; l += THREADS)
        e3S[l & 1][(l >> 2) * SSTR + ((l >> 1) & 1) * 11] = INF4;
    __syncthreads();

    float4 srcF[3], e1F[6], e2F[6], e3F[2], rxAF[2], rxBF[2], mxyAF[3], mxyBF[3], dAF[2];
    float4 sklF[6], othF[6];
#pragma unroll
    for (int i = 0; i < 3; ++i) srcF[i] = INF4;
#pragma unroll
    for (int i = 0; i < 6; ++i) { e1F[i] = INF4; e2F[i] = INF4; sklF[i] = ZERO4; othF[i] = ZERO4; }
    e3F[0] = e3F[1] = INF4;
    rxAF[0] = rxAF[1] = MINF4;
    rxBF[0] = rxBF[1] = MINF4;
    mxyAF[0] = mxyAF[1] = mxyAF[2] = MINF4;
    mxyBF[0] = mxyBF[1] = mxyBF[2] = MINF4;
    dAF[0] = dAF[1] = ZERO4;

    float accS = 0.f, accSO = 0.f;
    const int NSTEP = zlen + 10;

    for (int sb = 0; sb < NSTEP; sb += 6) {
#pragma unroll
        for (int u = 0; u < 6; ++u) {
            const int zL = z0 - 4 + (sb + u);
            const int sl  = u & 1;
            const int slp = sl ^ 1;

            {   // L(zL)
                float4 vv = INF4;
                if ((unsigned)zL < ND && zL < z0 + zlen + 4 && gOK)
                    vv = src4[zL * ZS4 + colBase];
                srcF[u % 3] = vv;
                if (tOK) srcS[sl][iSrc] = vv;
            }
            {   // prefetch skel/oth for OUT 3 steps ahead (z = zL-3)
                const int zp = zL - 3;
                const bool pOK = aC && zp >= z0 && zp < z0 + zlen;
                float4 sv = ZERO4;
                if (pOK) sv = skl4[zp * ZS4 + colBase];
                sklF[u] = sv;
                if (RED) {
                    float4 ov = ZERO4;
                    if (pOK) ov = oth4[zp * ZS4 + colBase];
                    othF[u] = ov;
                }
            }
            {   // E1(zL-1)
                const int z = zL - 1;
                float4 vv = INF4;
                if (aE1 && (unsigned)z < ND) {
                    const float4* S = srcS[slp];
                    float4 xm = f4winmin(S[iSrc - 1], srcF[(u + 2) % 3], S[iSrc + 1]);
                    vv = f4min(f4min(xm, S[iSrc - SSTR]),
                               f4min(S[iSrc + SSTR],
                                     f4min(srcF[(u + 1) % 3], srcF[u % 3])));
                }
                e1F[u % 6] = vv;
                if (aE1) e1S[sl][iE1] = vv;
            }
            {   // E2(zL-2) — img output
                const int z = zL - 2;
                float4 vv = INF4;
                if (aE2) {
                    const float4* S = e1S[slp];
                    float4 xm = f4winmin(S[iE1 - 1], e1F[(u + 5) % 6], S[iE1 + 1]);
                    vv = f4min(f4min(xm, S[iE1 - SSTR]),
                               f4min(S[iE1 + SSTR],
                                     f4min(e1F[(u + 4) % 6], e1F[u % 6])));
                    e2S[sl][iE2] = vv;
                    if (img4 && aC && z >= z0 && z < z0 + zlen)
                        img4[z * ZS4 + colBase] = vv;
                }
                e2F[u % 6] = vv;
            }
            {   // E3(zL-3)
                float4 vv = INF4;
                if (aE3) {
                    const float4* S = e2S[slp];
                    float4 xm = f4winmin(S[iE2 - 1], e2F[(u + 5) % 6], S[iE2 + 1]);
                    vv = f4min(f4min(xm, S[iE2 - SSTR]),
                               f4min(S[iE2 + SSTR],
                                     f4min(e2F[(u + 4) % 6], e2F[u % 6])));
                    e3S[sl][iE3] = vv;
                }
                e3F[u % 2] = vv;
            }
            {   // rxA(zL-3) from e2S[slp]; rxB(zL-4) from e3S[slp]
                float4 ra = MINF4, rb = MINF4;
                if (aRx) {
                    const float4* SA = e2S[slp];
                    const float4* SB = e3S[slp];
                    ra = f4winmax(SA[iE2 - 1], e2F[(u + 5) % 6], SA[iE2 + 1]);
                    rb = f4winmax(SB[iE3 - 1], e3F[(u + 1) % 2], SB[iE3 + 1]);
                    rxAS[sl][iRx] = ra;
                    rxBS[sl][iRx] = rb;
                }
                float4 mA = MINF4, mB = MINF4;
                if (aC) {
                    mA = f4max(f4max(rxAF[(u + 1) % 2], rxAS[slp][iRx - RSTR]),
                               rxAS[slp][iRx + RSTR]);
                    mB = f4max(f4max(rxBF[(u + 1) % 2], rxBS[slp][iRx - RSTR]),
                               rxBS[slp][iRx + RSTR]);
                }
                rxAF[u % 2] = ra;
                rxBF[u % 2] = rb;
                mxyAF[u % 3] = mA;
                mxyBF[u % 3] = mB;
            }
            {   // dA(zL-5) = relu(E1(zL-5) - dilA)
                float4 dilA = f4max(f4max(mxyAF[0], mxyAF[1]), mxyAF[2]);
                dAF[u % 2] = f4relu_sub(e1F[(u + 2) % 6], dilA);
            }
            {   // OUT(zL-6): apply dA then dB (skel value from prefetch FIFO)
                const int z = zL - 6;
                if (aC && z >= z0 && z < z0 + zlen) {
                    float4 dilB = f4max(f4max(mxyBF[0], mxyBF[1]), mxyBF[2]);
                    float4 dB = f4relu_sub(e2F[(u + 2) % 6], dilB);
                    float4 da = dAF[(u + 1) % 2];
                    int gi = z * ZS4 + colBase;
                    float4 sv = sklF[(u + 3) % 6];
                    float4 s1, s2;
                    s1.x = sv.x + fmaxf(da.x - sv.x * da.x, 0.f);
                    s1.y = sv.y + fmaxf(da.y - sv.y * da.y, 0.f);
                    s1.z = sv.z + fmaxf(da.z - sv.z * da.z, 0.f);
                    s1.w = sv.w + fmaxf(da.w - sv.w * da.w, 0.f);
                    s2.x = s1.x + fmaxf(dB.x - s1.x * dB.x, 0.f);
                    s2.y = s1.y + fmaxf(dB.y - s1.y * dB.y, 0.f);
                    s2.z = s1.z + fmaxf(dB.z - s1.z * dB.z, 0.f);
                    s2.w = s1.w + fmaxf(dB.w - s1.w * dB.w, 0.f);
                    skl4[gi] = s2;
                    if (RED) {
                        accS += s2.x + s2.y + s2.z + s2.w;
                        float4 o = othF[(u + 3) % 6];
                        accSO += s2.x * o.x + s2.y * o.y + s2.z * o.z + s2.w * o.w;
                    }
                }
            }
            __syncthreads();
        }
    }

    if (RED) {
        float* sbuf = (float*)srcS;
        float r1 = block_reduce(accS, sbuf);
        float r2 = block_reduce(accSO, sbuf);
        if (tid == 0) {
            int halfSel = (othB && v >= 4) ? 1 : 0;
            int A = (offBase + 2 * halfSel) * 1024;
            int zslot = chunk + zchunks * (v & 3);
            int bid = blockIdx.x + 4 * (blockIdx.y + 8 * zslot);
            part[A + bid] = r1;
            part[A + 1024 + bid] = r2;
        }
    }
}

// ---------------------------------------------------------------------------
// finalize: sum 7 partial arrays (1024 each) and compute the loss scalar
// ---------------------------------------------------------------------------
__global__ void finalize_kernel(const float* __restrict__ part, float* __restrict__ out) {
    __shared__ float sbuf[THREADS / 64];
    float s[7];
#pragma unroll
    for (int k = 0; k < 7; ++k) {
        float local = 0.f;
        for (int i = threadIdx.x; i < 1024; i += THREADS) local += part[k * 1024 + i];
        s[k] = block_reduce(local, sbuf);
    }
    if (threadIdx.x == 0) {
        const float smooth = 1.0f;
        const float alpha = 0.3f;
        float dice = 1.f - (2.f * s[2] + smooth) / (s[1] + s[0] + smooth);
        float tprec = (s[4] + smooth) / (s[3] + smooth);
        float tsens = (s[6] + smooth) / (s[5] + smooth);
        float cl = 1.f - 2.f * (tprec * tsens) / (tprec + tsens);
        out[0] = (1.f - alpha) * dice + alpha * cl;
    }
}

// ---------------------------------------------------------------------------
extern "C" void kernel_launch(void* const* d_in, const int* in_sizes, int n_in,
                              void* d_out, int out_size, void* d_ws, size_t ws_size,
                              hipStream_t stream) {
    const float* y_pred = (const float*)d_in[0];
    const float* y_true = (const float*)d_in[1];
    float* out = (float*)d_out;

    char* ws = (char*)d_ws;
    float* part = (float*)ws;                 // 7 * 1024 floats
    float* yp = (float*)(ws + 32768);
    const size_t NB4 = (size_t)NVOX;
    const size_t need_batched = 32768 + 7 * NB4 * sizeof(float);

    hipMemsetAsync(part, 0, 7 * 1024 * sizeof(float), stream);
    sigmoid_reduce_kernel<<<SIG_BLOCKS, THREADS, 0, stream>>>(
        (const float4*)y_pred, (const float4*)y_true, (float4*)yp, part);

    if (ws_size >= need_batched) {
        // batched: both skeletons (8 volumes) per dispatch
        float* ping = yp + NB4;          // 8-vol
        float* pong = ping + 2 * NB4;    // 8-vol
        float* S    = pong + 2 * NB4;    // 8-vol
        const int zc = 2;                // zlen 64 -> 512 blocks, fully co-resident
        dim3 grid(NW / TX, NH / TY, zc * 8);   // 4 x 8 x 16 = 512

        init_step_kernel<<<grid, THREADS, 0, stream>>>(yp, y_true, S, zc);

        float* bufs[2] = {ping, pong};
        for (int i = 0; i < 8; ++i) {
            const float* sA = (i == 0) ? yp : bufs[(i + 1) & 1];
            const float* sB = (i == 0) ? y_true : nullptr;
            float* oimg = (i < 7) ? bufs[i & 1] : nullptr;   // last pair: img dead
            if (i < 7)
                skel_pair_kernel<0><<<grid, THREADS, 0, stream>>>(
                    sA, sB, oimg, S, zc, nullptr, nullptr, nullptr, 0);
            else
                skel_pair_kernel<1><<<grid, THREADS, 0, stream>>>(
                    sA, sB, oimg, S, zc, y_true, yp, part, 3);
        }
    } else {
        // sequential fallback: one skeleton stream (4 vols) at a time
        float* ping = yp + NB4;
        float* pong = ping + NB4;
        float* Sp   = pong + NB4;
        float* St   = Sp + NB4;
        const int zc = 4;                // zlen 32 -> 512 blocks
        dim3 grid(NW / TX, NH / TY, zc * 4);

        auto run = [&](const float* x, float* S, const float* other, int offBase) {
            init_step_kernel<<<grid, THREADS, 0, stream>>>(x, nullptr, S, zc);
            float* bufs[2] = {ping, pong};
            for (int i = 0; i < 8; ++i) {
                const float* sA = (i == 0) ? x : bufs[(i + 1) & 1];
                float* oimg = (i < 7) ? bufs[i & 1] : nullptr;
                if (i < 7)
                    skel_pair_kernel<0><<<grid, THREADS, 0, stream>>>(
                        sA, nullptr, oimg, S, zc, nullptr, nullptr, nullptr, 0);
                else
                    skel_pair_kernel<1><<<grid, THREADS, 0, stream>>>(
                        sA, nullptr, oimg, S, zc, other, nullptr, part, offBase);
            }
        };
        run(yp, Sp, y_true, 3);
        run(y_true, St, yp, 5);
    }

    finalize_kernel<<<1, THREADS, 0, stream>>>(part, out);
}

// Round 10
// 984.694 us; speedup vs baseline: 1.5114x; 1.0599x over previous
//
#include <hip/hip_runtime.h>
#include <cmath>

// Volume: [B=4, C=1, D=128, H=128, W=128] fp32
#define NB 4
#define ND 128
#define NH 128
#define NW 128
#define NVOL_VOX (ND * NH * NW)    // 2097152 per volume
#define NVOX (NB * NVOL_VOX)       // 8388608 (4 volumes)

#define THREADS 256
#define TX 32
#define TY 16
#define SSTR 13
#define RSTR 9
#define ZS4 ((NH * NW) >> 2)       // 4096 f4 per z-slice

__device__ __forceinline__ float4 f4min(float4 a, float4 b) {
    return make_float4(fminf(a.x, b.x), fminf(a.y, b.y), fminf(a.z, b.z), fminf(a.w, b.w));
}
__device__ __forceinline__ float4 f4max(float4 a, float4 b) {
    return make_float4(fmaxf(a.x, b.x), fmaxf(a.y, b.y), fmaxf(a.z, b.z), fmaxf(a.w, b.w));
}
__device__ __forceinline__ float4 f4relu_sub(float4 a, float4 b) {
    return make_float4(fmaxf(a.x - b.x, 0.f), fmaxf(a.y - b.y, 0.f),
                       fmaxf(a.z - b.z, 0.f), fmaxf(a.w - b.w, 0.f));
}
// x-window ops taking boundary FLOATS (b32 LDS reads) instead of full f4
__device__ __forceinline__ float4 f4winmin_s(float lfw, float4 cc, float rtx) {
    float4 o;
    o.x = fminf(fminf(lfw, cc.x), cc.y);
    o.y = fminf(fminf(cc.x, cc.y), cc.z);
    o.z = fminf(fminf(cc.y, cc.z), cc.w);
    o.w = fminf(fminf(cc.z, cc.w), rtx);
    return o;
}
__device__ __forceinline__ float4 f4winmax_s(float lfw, float4 cc, float rtx) {
    float4 o;
    o.x = fmaxf(fmaxf(lfw, cc.x), cc.y);
    o.y = fmaxf(fmaxf(cc.x, cc.y), cc.z);
    o.z = fmaxf(fmaxf(cc.y, cc.z), cc.w);
    o.w = fmaxf(fmaxf(cc.z, cc.w), rtx);
    return o;
}

__device__ __forceinline__ float block_reduce(float v, float* sbuf) {
    for (int off = 32; off > 0; off >>= 1) v += __shfl_down(v, off, 64);
    int lane = threadIdx.x & 63;
    int wid  = threadIdx.x >> 6;
    if (lane == 0) sbuf[wid] = v;
    __syncthreads();
    float r = 0.f;
    if (wid == 0) {
        r = (lane < (int)(blockDim.x >> 6)) ? sbuf[lane] : 0.f;
        for (int off = 8; off > 0; off >>= 1) r += __shfl_down(r, off, 64);
    }
    __syncthreads();
    return r;
}

// ---------------------------------------------------------------------------
// sigmoid + dice partials
// ---------------------------------------------------------------------------
#define SIG_BLOCKS 1024
__global__ void sigmoid_reduce_kernel(const float4* __restrict__ logits,
                                      const float4* __restrict__ yt,
                                      float4* __restrict__ yp,
                                      float* __restrict__ part) {
    __shared__ float sbuf[THREADS / 64];
    const int n4 = NVOX / 4;
    float sp = 0.f, st = 0.f, stp = 0.f;
    for (int i = blockIdx.x * blockDim.x + threadIdx.x; i < n4;
         i += gridDim.x * blockDim.x) {
        float4 l = logits[i];
        float4 t = yt[i];
        float4 p;
        p.x = 1.f / (1.f + expf(-l.x));
        p.y = 1.f / (1.f + expf(-l.y));
        p.z = 1.f / (1.f + expf(-l.z));
        p.w = 1.f / (1.f + expf(-l.w));
        yp[i] = p;
        sp  += p.x + p.y + p.z + p.w;
        st  += t.x + t.y + t.z + t.w;
        stp += t.x * p.x + t.y * p.y + t.z * p.z + t.w * p.w;
    }
    float a = block_reduce(sp, sbuf);
    float b = block_reduce(st, sbuf);
    float c = block_reduce(stp, sbuf);
    if (threadIdx.x == 0) {
        part[blockIdx.x]        = a;
        part[1024 + blockIdx.x] = b;
        part[2048 + blockIdx.x] = c;
    }
}

// ---------------------------------------------------------------------------
// Fused skeleton kernel.
// INIT=0 (pair):  E1=erode(src); E2=erode(E1) [img]; E3=erode(E2)
//                 dA = relu(E1 - dilate(E2)); dB = relu(E2 - dilate(E3))
//                 s1 = s + relu(dA - s*dA); s2 = s1 + relu(dB - s1*dB)
//                 (skel/oth prefetched 3 z-steps ahead)
// INIT=1 (init+2 iters): additionally d0 = relu(src - dilate(E1)) via a
//                 third rx/mxy path (rxC over E1); s0 = d0 (no skel read).
// ---------------------------------------------------------------------------
template <int RED, int INIT>
__global__ __launch_bounds__(256, 2)
void skel_pair_kernel(const float* __restrict__ srcA, const float* __restrict__ srcB,
                      float* __restrict__ imgOut, float* __restrict__ skel,
                      int zchunks,
                      const float* __restrict__ othA, const float* __restrict__ othB,
                      float* __restrict__ part, int offBase) {
    __shared__ float4 srcS[2][24 * SSTR];
    __shared__ float4 e1S [2][22 * SSTR];
    __shared__ float4 e2S [2][20 * SSTR];
    __shared__ float4 e3S [2][18 * SSTR];
    __shared__ float4 rxAS[2][18 * RSTR];
    __shared__ float4 rxBS[2][18 * RSTR];
    __shared__ float4 rxCS[2][18 * RSTR];   // only used when INIT

    const float4 INF4  = make_float4(INFINITY, INFINITY, INFINITY, INFINITY);
    const float4 MINF4 = make_float4(-INFINITY, -INFINITY, -INFINITY, -INFINITY);
    const float4 ZERO4 = make_float4(0.f, 0.f, 0.f, 0.f);

    const int zlen  = ND / zchunks;
    const int v     = blockIdx.z / zchunks;
    const int chunk = blockIdx.z - v * zchunks;
    const int z0    = chunk * zlen;
    const int tx0   = blockIdx.x * TX;
    const int ty0   = blockIdx.y * TY;
    const int tid   = threadIdx.x;

    const float* src = srcB ? (v < 4 ? srcA + (size_t)v * NVOL_VOX
                                     : srcB + (size_t)(v - 4) * NVOL_VOX)
                            : srcA + (size_t)v * NVOL_VOX;
    const float4* src4 = (const float4*)src;
    float4* img4 = imgOut ? (float4*)(imgOut + (size_t)v * NVOL_VOX) : nullptr;
    float4* skl4 = (float4*)(skel + (size_t)v * NVOL_VOX);
    const float4* oth4 = nullptr;
    if (RED) {
        const float* oth = othB ? (v < 4 ? othA + (size_t)v * NVOL_VOX
                                         : othB + (size_t)(v - 4) * NVOL_VOX)
                                : othA + (size_t)v * NVOL_VOX;
        oth4 = (const float4*)oth;
    }

    const int fy = tid / 10, qx = tid - (tid / 10) * 10;   // rows 0..23
    const bool tOK = tid < 240;
    const bool aE1 = tOK && fy >= 1 && fy < 23;
    const bool aE2 = tOK && fy >= 2 && fy < 22;
    const bool aE3 = tOK && fy >= 3 && fy < 21;
    const bool aRx = aE3 && qx >= 1 && qx < 9;
    const bool aC  = tOK && fy >= 4 && fy < 20 && qx >= 1 && qx < 9;
    const int gy = ty0 + fy - 4;
    const int gx4 = tx0 + (qx - 1) * 4;
    const bool gOK = tOK && (unsigned)gy < NH && (unsigned)gx4 < NW;
    const int colBase = gOK ? ((gy * NW + gx4) >> 2) : 0;
    const int iSrc = fy * SSTR + qx + 1;
    const int iE1  = (fy - 1) * SSTR + qx + 1;
    const int iE2  = (fy - 2) * SSTR + qx + 1;
    const int iE3  = (fy - 3) * SSTR + qx + 1;
    const int iRx  = (fy - 3) * RSTR + (qx - 1);

    for (int l = tid; l < 2 * 24 * 2; l += THREADS)
        srcS[l & 1][(l >> 2) * SSTR + ((l >> 1) & 1) * 11] = INF4;
    for (int l = tid; l < 2 * 22 * 2; l += THREADS)
        e1S[l & 1][(l >> 2) * SSTR + ((l >> 1) & 1) * 11] = INF4;
    for (int l = tid; l < 2 * 20 * 2; l += THREADS)
        e2S[l & 1][(l >> 2) * SSTR + ((l >> 1) & 1) * 11] = INF4;
    for (int l = tid; l < 2 * 18 * 2; l += THREADS)
        e3S[l & 1][(l >> 2) * SSTR + ((l >> 1) & 1) * 11] = INF4;
    __syncthreads();

    constexpr int SD = INIT ? 6 : 3;
    float4 srcF[SD], e1F[6], e2F[6], e3F[2], rxAF[2], rxBF[2], mxyAF[3], mxyBF[3], dAF[2];
    float4 sklF[6], othF[6];
    float4 rxCF[2], mxyCF[3], d0F[3];
#pragma unroll
    for (int i = 0; i < SD; ++i) srcF[i] = INF4;
#pragma unroll
    for (int i = 0; i < 6; ++i) { e1F[i] = INF4; e2F[i] = INF4; sklF[i] = ZERO4; othF[i] = ZERO4; }
    e3F[0] = e3F[1] = INF4;
    rxAF[0] = rxAF[1] = MINF4;
    rxBF[0] = rxBF[1] = MINF4;
    rxCF[0] = rxCF[1] = MINF4;
    mxyAF[0] = mxyAF[1] = mxyAF[2] = MINF4;
    mxyBF[0] = mxyBF[1] = mxyBF[2] = MINF4;
    mxyCF[0] = mxyCF[1] = mxyCF[2] = MINF4;
    dAF[0] = dAF[1] = ZERO4;
    d0F[0] = d0F[1] = d0F[2] = ZERO4;

    float accS = 0.f, accSO = 0.f;
    const int NSTEP = zlen + 10;

    for (int sb = 0; sb < NSTEP; sb += 6) {
#pragma unroll
        for (int u = 0; u < 6; ++u) {
            const int zL = z0 - 4 + (sb + u);
            const int sl  = u & 1;
            const int slp = sl ^ 1;

            {   // L(zL)
                float4 vv = INF4;
                if ((unsigned)zL < ND && zL < z0 + zlen + 4 && gOK)
                    vv = src4[zL * ZS4 + colBase];
                srcF[u % SD] = vv;
                if (tOK) srcS[sl][iSrc] = vv;
            }
            if (!INIT) {   // prefetch skel/oth for OUT 3 steps ahead (z = zL-3)
                const int zp = zL - 3;
                const bool pOK = aC && zp >= z0 && zp < z0 + zlen;
                float4 sv = ZERO4;
                if (pOK) sv = skl4[zp * ZS4 + colBase];
                sklF[u] = sv;
                if (RED) {
                    float4 ov = ZERO4;
                    if (pOK) ov = oth4[zp * ZS4 + colBase];
                    othF[u] = ov;
                }
            }
            {   // E1(zL-1)
                const int z = zL - 1;
                float4 vv = INF4;
                if (aE1 && (unsigned)z < ND) {
                    const float4* S = srcS[slp];
                    const float* fS = (const float*)S;
                    float4 cc = INIT ? srcF[(u + 5) % 6] : srcF[(u + 2) % SD];
                    float4 zm = INIT ? f4min(srcF[(u + 4) % 6], srcF[u % 6])
                                     : f4min(srcF[(u + 1) % SD], srcF[u % SD]);
                    float4 xm = f4winmin_s(fS[4 * iSrc - 1], cc, fS[4 * iSrc + 4]);
                    vv = f4min(f4min(xm, S[iSrc - SSTR]),
                               f4min(S[iSrc + SSTR], zm));
                }
                e1F[u % 6] = vv;
                if (aE1) e1S[sl][iE1] = vv;
            }
            {   // E2(zL-2) — img output
                const int z = zL - 2;
                float4 vv = INF4;
                if (aE2) {
                    const float4* S = e1S[slp];
                    const float* fS = (const float*)S;
                    float4 xm = f4winmin_s(fS[4 * iE1 - 1], e1F[(u + 5) % 6], fS[4 * iE1 + 4]);
                    vv = f4min(f4min(xm, S[iE1 - SSTR]),
                               f4min(S[iE1 + SSTR],
                                     f4min(e1F[(u + 4) % 6], e1F[u % 6])));
                    e2S[sl][iE2] = vv;
                    if (img4 && aC && z >= z0 && z < z0 + zlen)
                        img4[z * ZS4 + colBase] = vv;
                }
                e2F[u % 6] = vv;
            }
            {   // E3(zL-3)
                float4 vv = INF4;
                if (aE3) {
                    const float4* S = e2S[slp];
                    const float* fS = (const float*)S;
                    float4 xm = f4winmin_s(fS[4 * iE2 - 1], e2F[(u + 5) % 6], fS[4 * iE2 + 4]);
                    vv = f4min(f4min(xm, S[iE2 - SSTR]),
                               f4min(S[iE2 + SSTR],
                                     f4min(e2F[(u + 4) % 6], e2F[u % 6])));
                    e3S[sl][iE3] = vv;
                }
                e3F[u % 2] = vv;
            }
            {   // rxA(zL-3) from e2S; rxB(zL-4) from e3S; [INIT] rxC(zL-2) from e1S
                float4 ra = MINF4, rb = MINF4, rc = MINF4;
                if (aRx) {
                    const float* fA = (const float*)e2S[slp];
                    const float* fB = (const float*)e3S[slp];
                    ra = f4winmax_s(fA[4 * iE2 - 1], e2F[(u + 5) % 6], fA[4 * iE2 + 4]);
                    rb = f4winmax_s(fB[4 * iE3 - 1], e3F[(u + 1) % 2], fB[4 * iE3 + 4]);
                    rxAS[sl][iRx] = ra;
                    rxBS[sl][iRx] = rb;
                    if (INIT) {
                        const float* fC = (const float*)e1S[slp];
                        rc = f4winmax_s(fC[4 * iE1 - 1], e1F[(u + 5) % 6], fC[4 * iE1 + 4]);
                        rxCS[sl][iRx] = rc;
                    }
                }
                float4 mA = MINF4, mB = MINF4, mC = MINF4;
                if (aC) {
                    mA = f4max(f4max(rxAF[(u + 1) % 2], rxAS[slp][iRx - RSTR]),
                               rxAS[slp][iRx + RSTR]);
                    mB = f4max(f4max(rxBF[(u + 1) % 2], rxBS[slp][iRx - RSTR]),
                               rxBS[slp][iRx + RSTR]);
                    if (INIT)
                        mC = f4max(f4max(rxCF[(u + 1) % 2], rxCS[slp][iRx - RSTR]),
                                   rxCS[slp][iRx + RSTR]);
                }
                rxAF[u % 2] = ra;
                rxBF[u % 2] = rb;
                mxyAF[u % 3] = mA;
                mxyBF[u % 3] = mB;
                if (INIT) { rxCF[u % 2] = rc; mxyCF[u % 3] = mC; }
            }
            if (INIT) {   // d0(zL-4) = relu(src(zL-4) - dilate(E1)(zL-4))
                float4 dilC = f4max(f4max(mxyCF[0], mxyCF[1]), mxyCF[2]);
                d0F[u % 3] = f4relu_sub(srcF[(u + 2) % 6], dilC);
            }
            {   // dA(zL-5) = relu(E1(zL-5) - dilA)
                float4 dilA = f4max(f4max(mxyAF[0], mxyAF[1]), mxyAF[2]);
                dAF[u % 2] = f4relu_sub(e1F[(u + 2) % 6], dilA);
            }
            {   // OUT(zL-6)
                const int z = zL - 6;
                if (aC && z >= z0 && z < z0 + zlen) {
                    float4 dilB = f4max(f4max(mxyBF[0], mxyBF[1]), mxyBF[2]);
                    float4 dB = f4relu_sub(e2F[(u + 2) % 6], dilB);
                    float4 da = dAF[(u + 1) % 2];
                    int gi = z * ZS4 + colBase;
                    float4 sv = INIT ? d0F[(u + 1) % 3] : sklF[(u + 3) % 6];
                    float4 s1, s2;
                    s1.x = sv.x + fmaxf(da.x - sv.x * da.x, 0.f);
                    s1.y = sv.y + fmaxf(da.y - sv.y * da.y, 0.f);
                    s1.z = sv.z + fmaxf(da.z - sv.z * da.z, 0.f);
                    s1.w = sv.w + fmaxf(da.w - sv.w * da.w, 0.f);
                    s2.x = s1.x + fmaxf(dB.x - s1.x * dB.x, 0.f);
                    s2.y = s1.y + fmaxf(dB.y - s1.y * dB.y, 0.f);
                    s2.z = s1.z + fmaxf(dB.z - s1.z * dB.z, 0.f);
                    s2.w = s1.w + fmaxf(dB.w - s1.w * dB.w, 0.f);
                    skl4[gi] = s2;
                    if (RED) {
                        accS += s2.x + s2.y + s2.z + s2.w;
                        float4 o = othF[(u + 3) % 6];
                        accSO += s2.x * o.x + s2.y * o.y + s2.z * o.z + s2.w * o.w;
                    }
                }
            }
            __syncthreads();
        }
    }

    if (RED) {
        float* sbuf = (float*)srcS;
        float r1 = block_reduce(accS, sbuf);
        float r2 = block_reduce(accSO, sbuf);
        if (tid == 0) {
            int halfSel = (othB && v >= 4) ? 1 : 0;
            int A = (offBase + 2 * halfSel) * 1024;
            int zslot = chunk + zchunks * (v & 3);
            int bid = blockIdx.x + 4 * (blockIdx.y + 8 * zslot);
            part[A + bid] = r1;
            part[A + 1024 + bid] = r2;
        }
    }
}

// ---------------------------------------------------------------------------
// finalize: sum 7 partial arrays (1024 each) and compute the loss scalar
// ---------------------------------------------------------------------------
__global__ void finalize_kernel(const float* __restrict__ part, float* __restrict__ out) {
    __shared__ float sbuf[THREADS / 64];
    float s[7];
#pragma unroll
    for (int k = 0; k < 7; ++k) {
        float local = 0.f;
        for (int i = threadIdx.x; i < 1024; i += THREADS) local += part[k * 1024 + i];
        s[k] = block_reduce(local, sbuf);
    }
    if (threadIdx.x == 0) {
        const float smooth = 1.0f;
        const float alpha = 0.3f;
        float dice = 1.f - (2.f * s[2] + smooth) / (s[1] + s[0] + smooth);
        float tprec = (s[4] + smooth) / (s[3] + smooth);
        float tsens = (s[6] + smooth) / (s[5] + smooth);
        float cl = 1.f - 2.f * (tprec * tsens) / (tprec + tsens);
        out[0] = (1.f - alpha) * dice + alpha * cl;
    }
}

// ---------------------------------------------------------------------------
extern "C" void kernel_launch(void* const* d_in, const int* in_sizes, int n_in,
                              void* d_out, int out_size, void* d_ws, size_t ws_size,
                              hipStream_t stream) {
    const float* y_pred = (const float*)d_in[0];
    const float* y_true = (const float*)d_in[1];
    float* out = (float*)d_out;

    char* ws = (char*)d_ws;
    float* part = (float*)ws;                 // 7 * 1024 floats
    float* yp = (float*)(ws + 32768);
    const size_t NB4 = (size_t)NVOX;
    const size_t need_batched = 32768 + 7 * NB4 * sizeof(float);

    hipMemsetAsync(part, 0, 7 * 1024 * sizeof(float), stream);
    sigmoid_reduce_kernel<<<SIG_BLOCKS, THREADS, 0, stream>>>(
        (const float4*)y_pred, (const float4*)y_true, (float4*)yp, part);

    if (ws_size >= need_batched) {
        // batched: both skeletons (8 volumes) per dispatch
        float* ping = yp + NB4;          // 8-vol
        float* pong = ping + 2 * NB4;    // 8-vol
        float* S    = pong + 2 * NB4;    // 8-vol
        const int zc = 2;                // zlen 64 -> 512 blocks, fully co-resident
        dim3 grid(NW / TX, NH / TY, zc * 8);   // 4 x 8 x 16 = 512

        // init + iters 1-2 fused; img out = E2
        skel_pair_kernel<0, 1><<<grid, THREADS, 0, stream>>>(
            yp, y_true, ping, S, zc, nullptr, nullptr, nullptr, 0);

        float* bufs[2] = {ping, pong};
        for (int j = 0; j < 7; ++j) {         // iters 3-16 (7 pairs)
            const float* sA = bufs[j & 1];
            float* oimg = (j < 6) ? bufs[(j + 1) & 1] : nullptr;
            if (j < 6)
                skel_pair_kernel<0, 0><<<grid, THREADS, 0, stream>>>(
                    sA, nullptr, oimg, S, zc, nullptr, nullptr, nullptr, 0);
            else
                skel_pair_kernel<1, 0><<<grid, THREADS, 0, stream>>>(
                    sA, nullptr, oimg, S, zc, y_true, yp, part, 3);
        }
    } else {
        // sequential fallback: one skeleton stream (4 vols) at a time
        float* ping = yp + NB4;
        float* pong = ping + NB4;
        float* Sp   = pong + NB4;
        float* St   = Sp + NB4;
        const int zc = 4;                // zlen 32 -> 512 blocks
        dim3 grid(NW / TX, NH / TY, zc * 4);

        auto run = [&](const float* x, float* S, const float* other, int offBase) {
            skel_pair_kernel<0, 1><<<grid, THREADS, 0, stream>>>(
                x, nullptr, ping, S, zc, nullptr, nullptr, nullptr, 0);
            float* bufs[2] = {ping, pong};
            for (int j = 0; j < 7; ++j) {
                const float* sA = bufs[j & 1];
                float* oimg = (j < 6) ? bufs[(j + 1) & 1] : nullptr;
                if (j < 6)
                    skel_pair_kernel<0, 0><<<grid, THREADS, 0, stream>>>(
                        sA, nullptr, oimg, S, zc, nullptr, nullptr, nullptr, 0);
                else
                    skel_pair_kernel<1, 0><<<grid, THREADS, 0, stream>>>(
                        sA, nullptr, oimg, S, zc, other, nullptr, part, offBase);
            }
        };
        run(yp, Sp, y_true, 3);
        run(y_true, St, yp, 5);
    }

    finalize_kernel<<<1, THREADS, 0, stream>>>(part, out);
}

// Round 11
// 964.678 us; speedup vs baseline: 1.5428x; 1.0207x over previous
//
#include <hip/hip_runtime.h>
#include <cmath>

// Volume: [B=4, C=1, D=128, H=128, W=128] fp32
#define NB 4
#define ND 128
#define NH 128
#define NW 128
#define NVOL_VOX (ND * NH * NW)    // 2097152 per volume
#define NVOX (NB * NVOL_VOX)       // 8388608 (4 volumes)

#define THREADS 256
#define TX 32
#define TY 16
// f4 strides chosen so stride ≡ 10 (row width) mod 8:
//   offset = fy*STR + qx + c = tid + 8*fy + c  -> every b128 8-lane phase is a
//   consecutive-offset run mod 8 => zero bank-phase conflicts for c, ±1, ±STR.
#define SSTR 18
#define RSTR 10
#define ZS4 ((NH * NW) >> 2)       // 4096 f4 per z-slice

__device__ __forceinline__ float4 f4min(float4 a, float4 b) {
    return make_float4(fminf(a.x, b.x), fminf(a.y, b.y), fminf(a.z, b.z), fminf(a.w, b.w));
}
__device__ __forceinline__ float4 f4max(float4 a, float4 b) {
    return make_float4(fmaxf(a.x, b.x), fmaxf(a.y, b.y), fmaxf(a.z, b.z), fmaxf(a.w, b.w));
}
__device__ __forceinline__ float4 f4relu_sub(float4 a, float4 b) {
    return make_float4(fmaxf(a.x - b.x, 0.f), fmaxf(a.y - b.y, 0.f),
                       fmaxf(a.z - b.z, 0.f), fmaxf(a.w - b.w, 0.f));
}
__device__ __forceinline__ float4 f4winmin(float4 lf, float4 cc, float4 rt) {
    float4 o;
    o.x = fminf(fminf(lf.w, cc.x), cc.y);
    o.y = fminf(fminf(cc.x, cc.y), cc.z);
    o.z = fminf(fminf(cc.y, cc.z), cc.w);
    o.w = fminf(fminf(cc.z, cc.w), rt.x);
    return o;
}
__device__ __forceinline__ float4 f4winmax(float4 lf, float4 cc, float4 rt) {
    float4 o;
    o.x = fmaxf(fmaxf(lf.w, cc.x), cc.y);
    o.y = fmaxf(fmaxf(cc.x, cc.y), cc.z);
    o.z = fmaxf(fmaxf(cc.y, cc.z), cc.w);
    o.w = fmaxf(fmaxf(cc.z, cc.w), rt.x);
    return o;
}

__device__ __forceinline__ float block_reduce(float v, float* sbuf) {
    for (int off = 32; off > 0; off >>= 1) v += __shfl_down(v, off, 64);
    int lane = threadIdx.x & 63;
    int wid  = threadIdx.x >> 6;
    if (lane == 0) sbuf[wid] = v;
    __syncthreads();
    float r = 0.f;
    if (wid == 0) {
        r = (lane < (int)(blockDim.x >> 6)) ? sbuf[lane] : 0.f;
        for (int off = 8; off > 0; off >>= 1) r += __shfl_down(r, off, 64);
    }
    __syncthreads();
    return r;
}

// ---------------------------------------------------------------------------
// sigmoid + dice partials
// ---------------------------------------------------------------------------
#define SIG_BLOCKS 1024
__global__ void sigmoid_reduce_kernel(const float4* __restrict__ logits,
                                      const float4* __restrict__ yt,
                                      float4* __restrict__ yp,
                                      float* __restrict__ part) {
    __shared__ float sbuf[THREADS / 64];
    const int n4 = NVOX / 4;
    float sp = 0.f, st = 0.f, stp = 0.f;
    for (int i = blockIdx.x * blockDim.x + threadIdx.x; i < n4;
         i += gridDim.x * blockDim.x) {
        float4 l = logits[i];
        float4 t = yt[i];
        float4 p;
        p.x = 1.f / (1.f + expf(-l.x));
        p.y = 1.f / (1.f + expf(-l.y));
        p.z = 1.f / (1.f + expf(-l.z));
        p.w = 1.f / (1.f + expf(-l.w));
        yp[i] = p;
        sp  += p.x + p.y + p.z + p.w;
        st  += t.x + t.y + t.z + t.w;
        stp += t.x * p.x + t.y * p.y + t.z * p.z + t.w * p.w;
    }
    float a = block_reduce(sp, sbuf);
    float b = block_reduce(st, sbuf);
    float c = block_reduce(stp, sbuf);
    if (threadIdx.x == 0) {
        part[blockIdx.x]        = a;
        part[1024 + blockIdx.x] = b;
        part[2048 + blockIdx.x] = c;
    }
}

// ---------------------------------------------------------------------------
// Fused skeleton kernel.
// INIT=0 (pair):  E1=erode(src); E2=erode(E1) [img]; E3=erode(E2)
//                 dA = relu(E1 - dilate(E2)); dB = relu(E2 - dilate(E3))
//                 s1 = s + relu(dA - s*dA); s2 = s1 + relu(dB - s1*dB)
//                 (skel/oth prefetched 3 z-steps ahead)
// INIT=1 (init+2 iters): additionally d0 = relu(src - dilate(E1)) via a
//                 third rx/mxy path (rxC over E1); s0 = d0 (no skel read).
// ---------------------------------------------------------------------------
template <int RED, int INIT>
__global__ __launch_bounds__(256, 2)
void skel_pair_kernel(const float* __restrict__ srcA, const float* __restrict__ srcB,
                      float* __restrict__ imgOut, float* __restrict__ skel,
                      int zchunks,
                      const float* __restrict__ othA, const float* __restrict__ othB,
                      float* __restrict__ part, int offBase) {
    __shared__ float4 srcS[2][24 * SSTR];
    __shared__ float4 e1S [2][22 * SSTR];
    __shared__ float4 e2S [2][20 * SSTR];
    __shared__ float4 e3S [2][18 * SSTR];
    __shared__ float4 rxAS[2][18 * RSTR];
    __shared__ float4 rxBS[2][18 * RSTR];
    __shared__ float4 rxCS[2][18 * RSTR];   // only used when INIT

    const float4 INF4  = make_float4(INFINITY, INFINITY, INFINITY, INFINITY);
    const float4 MINF4 = make_float4(-INFINITY, -INFINITY, -INFINITY, -INFINITY);
    const float4 ZERO4 = make_float4(0.f, 0.f, 0.f, 0.f);

    const int zlen  = ND / zchunks;
    const int v     = blockIdx.z / zchunks;
    const int chunk = blockIdx.z - v * zchunks;
    const int z0    = chunk * zlen;
    const int tx0   = blockIdx.x * TX;
    const int ty0   = blockIdx.y * TY;
    const int tid   = threadIdx.x;

    const float* src = srcB ? (v < 4 ? srcA + (size_t)v * NVOL_VOX
                                     : srcB + (size_t)(v - 4) * NVOL_VOX)
                            : srcA + (size_t)v * NVOL_VOX;
    const float4* src4 = (const float4*)src;
    float4* img4 = imgOut ? (float4*)(imgOut + (size_t)v * NVOL_VOX) : nullptr;
    float4* skl4 = (float4*)(skel + (size_t)v * NVOL_VOX);
    const float4* oth4 = nullptr;
    if (RED) {
        const float* oth = othB ? (v < 4 ? othA + (size_t)v * NVOL_VOX
                                         : othB + (size_t)(v - 4) * NVOL_VOX)
                                : othA + (size_t)v * NVOL_VOX;
        oth4 = (const float4*)oth;
    }

    const int fy = tid / 10, qx = tid - (tid / 10) * 10;   // rows 0..23
    const bool tOK = tid < 240;
    const bool aE1 = tOK && fy >= 1 && fy < 23;
    const bool aE2 = tOK && fy >= 2 && fy < 22;
    const bool aE3 = tOK && fy >= 3 && fy < 21;
    const bool aRx = aE3 && qx >= 1 && qx < 9;
    const bool aC  = tOK && fy >= 4 && fy < 20 && qx >= 1 && qx < 9;
    const int gy = ty0 + fy - 4;
    const int gx4 = tx0 + (qx - 1) * 4;
    const bool gOK = tOK && (unsigned)gy < NH && (unsigned)gx4 < NW;
    const int colBase = gOK ? ((gy * NW + gx4) >> 2) : 0;
    const int iSrc = fy * SSTR + qx + 1;
    const int iE1  = (fy - 1) * SSTR + qx + 1;
    const int iE2  = (fy - 2) * SSTR + qx + 1;
    const int iE3  = (fy - 3) * SSTR + qx + 1;
    const int iRx  = (fy - 3) * RSTR + (qx - 1);

    // guards at cols 0 and 11 (data cols 1..10; cols 12..17 pad, never read)
    for (int l = tid; l < 2 * 24 * 2; l += THREADS)
        srcS[l & 1][(l >> 2) * SSTR + ((l >> 1) & 1) * 11] = INF4;
    for (int l = tid; l < 2 * 22 * 2; l += THREADS)
        e1S[l & 1][(l >> 2) * SSTR + ((l >> 1) & 1) * 11] = INF4;
    for (int l = tid; l < 2 * 20 * 2; l += THREADS)
        e2S[l & 1][(l >> 2) * SSTR + ((l >> 1) & 1) * 11] = INF4;
    for (int l = tid; l < 2 * 18 * 2; l += THREADS)
        e3S[l & 1][(l >> 2) * SSTR + ((l >> 1) & 1) * 11] = INF4;
    __syncthreads();

    constexpr int SD = INIT ? 6 : 3;
    float4 srcF[SD], e1F[6], e2F[6], e3F[2], rxAF[2], rxBF[2], mxyAF[3], mxyBF[3], dAF[2];
    float4 sklF[6], othF[6];
    float4 rxCF[2], mxyCF[3], d0F[3];
#pragma unroll
    for (int i = 0; i < SD; ++i) srcF[i] = INF4;
#pragma unroll
    for (int i = 0; i < 6; ++i) { e1F[i] = INF4; e2F[i] = INF4; sklF[i] = ZERO4; othF[i] = ZERO4; }
    e3F[0] = e3F[1] = INF4;
    rxAF[0] = rxAF[1] = MINF4;
    rxBF[0] = rxBF[1] = MINF4;
    rxCF[0] = rxCF[1] = MINF4;
    mxyAF[0] = mxyAF[1] = mxyAF[2] = MINF4;
    mxyBF[0] = mxyBF[1] = mxyBF[2] = MINF4;
    mxyCF[0] = mxyCF[1] = mxyCF[2] = MINF4;
    dAF[0] = dAF[1] = ZERO4;
    d0F[0] = d0F[1] = d0F[2] = ZERO4;

    float accS = 0.f, accSO = 0.f;
    const int NSTEP = zlen + 10;

    for (int sb = 0; sb < NSTEP; sb += 6) {
#pragma unroll
        for (int u = 0; u < 6; ++u) {
            const int zL = z0 - 4 + (sb + u);
            const int sl  = u & 1;
            const int slp = sl ^ 1;

            {   // L(zL)
                float4 vv = INF4;
                if ((unsigned)zL < ND && zL < z0 + zlen + 4 && gOK)
                    vv = src4[zL * ZS4 + colBase];
                srcF[u % SD] = vv;
                if (tOK) srcS[sl][iSrc] = vv;
            }
            if (!INIT) {   // prefetch skel/oth for OUT 3 steps ahead (z = zL-3)
                const int zp = zL - 3;
                const bool pOK = aC && zp >= z0 && zp < z0 + zlen;
                float4 sv = ZERO4;
                if (pOK) sv = skl4[zp * ZS4 + colBase];
                sklF[u] = sv;
                if (RED) {
                    float4 ov = ZERO4;
                    if (pOK) ov = oth4[zp * ZS4 + colBase];
                    othF[u] = ov;
                }
            }
            {   // E1(zL-1)
                const int z = zL - 1;
                float4 vv = INF4;
                if (aE1 && (unsigned)z < ND) {
                    const float4* S = srcS[slp];
                    float4 cc = INIT ? srcF[(u + 5) % 6] : srcF[(u + 2) % SD];
                    float4 zm = INIT ? f4min(srcF[(u + 4) % 6], srcF[u % 6])
                                     : f4min(srcF[(u + 1) % SD], srcF[u % SD]);
                    float4 xm = f4winmin(S[iSrc - 1], cc, S[iSrc + 1]);
                    vv = f4min(f4min(xm, S[iSrc - SSTR]),
                               f4min(S[iSrc + SSTR], zm));
                }
                e1F[u % 6] = vv;
                if (aE1) e1S[sl][iE1] = vv;
            }
            {   // E2(zL-2) — img output
                const int z = zL - 2;
                float4 vv = INF4;
                if (aE2) {
                    const float4* S = e1S[slp];
                    float4 xm = f4winmin(S[iE1 - 1], e1F[(u + 5) % 6], S[iE1 + 1]);
                    vv = f4min(f4min(xm, S[iE1 - SSTR]),
                               f4min(S[iE1 + SSTR],
                                     f4min(e1F[(u + 4) % 6], e1F[u % 6])));
                    e2S[sl][iE2] = vv;
                    if (img4 && aC && z >= z0 && z < z0 + zlen)
                        img4[z * ZS4 + colBase] = vv;
                }
                e2F[u % 6] = vv;
            }
            {   // E3(zL-3)
                float4 vv = INF4;
                if (aE3) {
                    const float4* S = e2S[slp];
                    float4 xm = f4winmin(S[iE2 - 1], e2F[(u + 5) % 6], S[iE2 + 1]);
                    vv = f4min(f4min(xm, S[iE2 - SSTR]),
                               f4min(S[iE2 + SSTR],
                                     f4min(e2F[(u + 4) % 6], e2F[u % 6])));
                    e3S[sl][iE3] = vv;
                }
                e3F[u % 2] = vv;
            }
            {   // rxA(zL-3) from e2S; rxB(zL-4) from e3S; [INIT] rxC(zL-2) from e1S
                float4 ra = MINF4, rb = MINF4, rc = MINF4;
                if (aRx) {
                    const float4* SA = e2S[slp];
                    const float4* SB = e3S[slp];
                    ra = f4winmax(SA[iE2 - 1], e2F[(u + 5) % 6], SA[iE2 + 1]);
                    rb = f4winmax(SB[iE3 - 1], e3F[(u + 1) % 2], SB[iE3 + 1]);
                    rxAS[sl][iRx] = ra;
                    rxBS[sl][iRx] = rb;
                    if (INIT) {
                        const float4* SC = e1S[slp];
                        rc = f4winmax(SC[iE1 - 1], e1F[(u + 5) % 6], SC[iE1 + 1]);
                        rxCS[sl][iRx] = rc;
                    }
                }
                float4 mA = MINF4, mB = MINF4, mC = MINF4;
                if (aC) {
                    mA = f4max(f4max(rxAF[(u + 1) % 2], rxAS[slp][iRx - RSTR]),
                               rxAS[slp][iRx + RSTR]);
                    mB = f4max(f4max(rxBF[(u + 1) % 2], rxBS[slp][iRx - RSTR]),
                               rxBS[slp][iRx + RSTR]);
                    if (INIT)
                        mC = f4max(f4max(rxCF[(u + 1) % 2], rxCS[slp][iRx - RSTR]),
                                   rxCS[slp][iRx + RSTR]);
                }
                rxAF[u % 2] = ra;
                rxBF[u % 2] = rb;
                mxyAF[u % 3] = mA;
                mxyBF[u % 3] = mB;
                if (INIT) { rxCF[u % 2] = rc; mxyCF[u % 3] = mC; }
            }
            if (INIT) {   // d0(zL-4) = relu(src(zL-4) - dilate(E1)(zL-4))
                float4 dilC = f4max(f4max(mxyCF[0], mxyCF[1]), mxyCF[2]);
                d0F[u % 3] = f4relu_sub(srcF[(u + 2) % 6], dilC);
            }
            {   // dA(zL-5) = relu(E1(zL-5) - dilA)
                float4 dilA = f4max(f4max(mxyAF[0], mxyAF[1]), mxyAF[2]);
                dAF[u % 2] = f4relu_sub(e1F[(u + 2) % 6], dilA);
            }
            {   // OUT(zL-6)
                const int z = zL - 6;
                if (aC && z >= z0 && z < z0 + zlen) {
                    float4 dilB = f4max(f4max(mxyBF[0], mxyBF[1]), mxyBF[2]);
                    float4 dB = f4relu_sub(e2F[(u + 2) % 6], dilB);
                    float4 da = dAF[(u + 1) % 2];
                    int gi = z * ZS4 + colBase;
                    float4 sv = INIT ? d0F[(u + 1) % 3] : sklF[(u + 3) % 6];
                    float4 s1, s2;
                    s1.x = sv.x + fmaxf(da.x - sv.x * da.x, 0.f);
                    s1.y = sv.y + fmaxf(da.y - sv.y * da.y, 0.f);
                    s1.z = sv.z + fmaxf(da.z - sv.z * da.z, 0.f);
                    s1.w = sv.w + fmaxf(da.w - sv.w * da.w, 0.f);
                    s2.x = s1.x + fmaxf(dB.x - s1.x * dB.x, 0.f);
                    s2.y = s1.y + fmaxf(dB.y - s1.y * dB.y, 0.f);
                    s2.z = s1.z + fmaxf(dB.z - s1.z * dB.z, 0.f);
                    s2.w = s1.w + fmaxf(dB.w - s1.w * dB.w, 0.f);
                    skl4[gi] = s2;
                    if (RED) {
                        accS += s2.x + s2.y + s2.z + s2.w;
                        float4 o = othF[(u + 3) % 6];
                        accSO += s2.x * o.x + s2.y * o.y + s2.z * o.z + s2.w * o.w;
                    }
                }
            }
            __syncthreads();
        }
    }

    if (RED) {
        float* sbuf = (float*)srcS;
        float r1 = block_reduce(accS, sbuf);
        float r2 = block_reduce(accSO, sbuf);
        if (tid == 0) {
            int halfSel = (othB && v >= 4) ? 1 : 0;
            int A = (offBase + 2 * halfSel) * 1024;
            int zslot = chunk + zchunks * (v & 3);
            int bid = blockIdx.x + 4 * (blockIdx.y + 8 * zslot);
            part[A + bid] = r1;
            part[A + 1024 + bid] = r2;
        }
    }
}

// ---------------------------------------------------------------------------
// finalize: sum 7 partial arrays (1024 each) and compute the loss scalar
// ---------------------------------------------------------------------------
__global__ void finalize_kernel(const float* __restrict__ part, float* __restrict__ out) {
    __shared__ float sbuf[THREADS / 64];
    float s[7];
#pragma unroll
    for (int k = 0; k < 7; ++k) {
        float local = 0.f;
        for (int i = threadIdx.x; i < 1024; i += THREADS) local += part[k * 1024 + i];
        s[k] = block_reduce(local, sbuf);
    }
    if (threadIdx.x == 0) {
        const float smooth = 1.0f;
        const float alpha = 0.3f;
        float dice = 1.f - (2.f * s[2] + smooth) / (s[1] + s[0] + smooth);
        float tprec = (s[4] + smooth) / (s[3] + smooth);
        float tsens = (s[6] + smooth) / (s[5] + smooth);
        float cl = 1.f - 2.f * (tprec * tsens) / (tprec + tsens);
        out[0] = (1.f - alpha) * dice + alpha * cl;
    }
}

// ---------------------------------------------------------------------------
extern "C" void kernel_launch(void* const* d_in, const int* in_sizes, int n_in,
                              void* d_out, int out_size, void* d_ws, size_t ws_size,
                              hipStream_t stream) {
    const float* y_pred = (const float*)d_in[0];
    const float* y_true = (const float*)d_in[1];
    float* out = (float*)d_out;

    char* ws = (char*)d_ws;
    float* part = (float*)ws;                 // 7 * 1024 floats
    float* yp = (float*)(ws + 32768);
    const size_t NB4 = (size_t)NVOX;
    const size_t need_batched = 32768 + 7 * NB4 * sizeof(float);

    hipMemsetAsync(part, 0, 7 * 1024 * sizeof(float), stream);
    sigmoid_reduce_kernel<<<SIG_BLOCKS, THREADS, 0, stream>>>(
        (const float4*)y_pred, (const float4*)y_true, (float4*)yp, part);

    if (ws_size >= need_batched) {
        // batched: both skeletons (8 volumes) per dispatch
        float* ping = yp + NB4;          // 8-vol
        float* pong = ping + 2 * NB4;    // 8-vol
        float* S    = pong + 2 * NB4;    // 8-vol
        const int zc = 2;                // zlen 64 -> 512 blocks, fully co-resident
        dim3 grid(NW / TX, NH / TY, zc * 8);   // 4 x 8 x 16 = 512

        // init + iters 1-2 fused; img out = E2
        skel_pair_kernel<0, 1><<<grid, THREADS, 0, stream>>>(
            yp, y_true, ping, S, zc, nullptr, nullptr, nullptr, 0);

        float* bufs[2] = {ping, pong};
        for (int j = 0; j < 7; ++j) {         // iters 3-16 (7 pairs)
            const float* sA = bufs[j & 1];
            float* oimg = (j < 6) ? bufs[(j + 1) & 1] : nullptr;
            if (j < 6)
                skel_pair_kernel<0, 0><<<grid, THREADS, 0, stream>>>(
                    sA, nullptr, oimg, S, zc, nullptr, nullptr, nullptr, 0);
            else
                skel_pair_kernel<1, 0><<<grid, THREADS, 0, stream>>>(
                    sA, nullptr, oimg, S, zc, y_true, yp, part, 3);
        }
    } else {
        // sequential fallback: one skeleton stream (4 vols) at a time
        float* ping = yp + NB4;
        float* pong = ping + NB4;
        float* Sp   = pong + NB4;
        float* St   = Sp + NB4;
        const int zc = 4;                // zlen 32 -> 512 blocks
        dim3 grid(NW / TX, NH / TY, zc * 4);

        auto run = [&](const float* x, float* S, const float* other, int offBase) {
            skel_pair_kernel<0, 1><<<grid, THREADS, 0, stream>>>(
                x, nullptr, ping, S, zc, nullptr, nullptr, nullptr, 0);
            float* bufs[2] = {ping, pong};
            for (int j = 0; j < 7; ++j) {
                const float* sA = bufs[j & 1];
                float* oimg = (j < 6) ? bufs[(j + 1) & 1] : nullptr;
                if (j < 6)
                    skel_pair_kernel<0, 0><<<grid, THREADS, 0, stream>>>(
                        sA, nullptr, oimg, S, zc, nullptr, nullptr, nullptr, 0);
                else
                    skel_pair_kernel<1, 0><<<grid, THREADS, 0, stream>>>(
                        sA, nullptr, oimg, S, zc, other, nullptr, part, offBase);
            }
        };
        run(yp, Sp, y_true, 3);
        run(y_true, St, yp, 5);
    }

    finalize_kernel<<<1, THREADS, 0, stream>>>(part, out);
}

// Round 12
// 945.091 us; speedup vs baseline: 1.5748x; 1.0207x over previous
//
#include <hip/hip_runtime.h>
#include <cmath>

// Volume: [B=4, C=1, D=128, H=128, W=128] fp32
#define NB 4
#define ND 128
#define NH 128
#define NW 128
#define NVOL_VOX (ND * NH * NW)    // 2097152 per volume
#define NVOX (NB * NVOL_VOX)       // 8388608 (4 volumes)

#define THREADS 256
#define TX 32
#define TY 16
// f4 strides ≡ 10 (row width) mod 8 -> b128 phases are consecutive mod 8 => conflict-free
#define SSTR 18
#define RSTR 10
#define ZS4 ((NH * NW) >> 2)       // 4096 f4 per z-slice

__device__ __forceinline__ float4 f4min(float4 a, float4 b) {
    return make_float4(fminf(a.x, b.x), fminf(a.y, b.y), fminf(a.z, b.z), fminf(a.w, b.w));
}
__device__ __forceinline__ float4 f4max(float4 a, float4 b) {
    return make_float4(fmaxf(a.x, b.x), fmaxf(a.y, b.y), fmaxf(a.z, b.z), fmaxf(a.w, b.w));
}
__device__ __forceinline__ float4 f4relu_sub(float4 a, float4 b) {
    return make_float4(fmaxf(a.x - b.x, 0.f), fmaxf(a.y - b.y, 0.f),
                       fmaxf(a.z - b.z, 0.f), fmaxf(a.w - b.w, 0.f));
}
// x-window ops with scalar boundary floats (b32 LDS reads)
__device__ __forceinline__ float4 f4winmin_s(float lfw, float4 cc, float rtx) {
    float4 o;
    o.x = fminf(fminf(lfw, cc.x), cc.y);
    o.y = fminf(fminf(cc.x, cc.y), cc.z);
    o.z = fminf(fminf(cc.y, cc.z), cc.w);
    o.w = fminf(fminf(cc.z, cc.w), rtx);
    return o;
}
__device__ __forceinline__ float4 f4winmax_s(float lfw, float4 cc, float rtx) {
    float4 o;
    o.x = fmaxf(fmaxf(lfw, cc.x), cc.y);
    o.y = fmaxf(fmaxf(cc.x, cc.y), cc.z);
    o.z = fmaxf(fmaxf(cc.y, cc.z), cc.w);
    o.w = fmaxf(fmaxf(cc.z, cc.w), rtx);
    return o;
}

__device__ __forceinline__ float block_reduce(float v, float* sbuf) {
    for (int off = 32; off > 0; off >>= 1) v += __shfl_down(v, off, 64);
    int lane = threadIdx.x & 63;
    int wid  = threadIdx.x >> 6;
    if (lane == 0) sbuf[wid] = v;
    __syncthreads();
    float r = 0.f;
    if (wid == 0) {
        r = (lane < (int)(blockDim.x >> 6)) ? sbuf[lane] : 0.f;
        for (int off = 8; off > 0; off >>= 1) r += __shfl_down(r, off, 64);
    }
    __syncthreads();
    return r;
}

// ---------------------------------------------------------------------------
// sigmoid + dice partials
// ---------------------------------------------------------------------------
#define SIG_BLOCKS 1024
__global__ void sigmoid_reduce_kernel(const float4* __restrict__ logits,
                                      const float4* __restrict__ yt,
                                      float4* __restrict__ yp,
                                      float* __restrict__ part) {
    __shared__ float sbuf[THREADS / 64];
    const int n4 = NVOX / 4;
    float sp = 0.f, st = 0.f, stp = 0.f;
    for (int i = blockIdx.x * blockDim.x + threadIdx.x; i < n4;
         i += gridDim.x * blockDim.x) {
        float4 l = logits[i];
        float4 t = yt[i];
        float4 p;
        p.x = 1.f / (1.f + expf(-l.x));
        p.y = 1.f / (1.f + expf(-l.y));
        p.z = 1.f / (1.f + expf(-l.z));
        p.w = 1.f / (1.f + expf(-l.w));
        yp[i] = p;
        sp  += p.x + p.y + p.z + p.w;
        st  += t.x + t.y + t.z + t.w;
        stp += t.x * p.x + t.y * p.y + t.z * p.z + t.w * p.w;
    }
    float a = block_reduce(sp, sbuf);
    float b = block_reduce(st, sbuf);
    float c = block_reduce(stp, sbuf);
    if (threadIdx.x == 0) {
        part[blockIdx.x]        = a;
        part[1024 + blockIdx.x] = b;
        part[2048 + blockIdx.x] = c;
    }
}

// ---------------------------------------------------------------------------
// Fused skeleton kernel (pair of iterations; INIT also folds the init step).
// ---------------------------------------------------------------------------
template <int RED, int INIT>
__global__ __launch_bounds__(256, 2)
void skel_pair_kernel(const float* __restrict__ srcA, const float* __restrict__ srcB,
                      float* __restrict__ imgOut, float* __restrict__ skel,
                      int zchunks,
                      const float* __restrict__ othA, const float* __restrict__ othB,
                      float* __restrict__ part, int offBase) {
    __shared__ float4 srcS[2][24 * SSTR];
    __shared__ float4 e1S [2][22 * SSTR];
    __shared__ float4 e2S [2][20 * SSTR];
    __shared__ float4 e3S [2][18 * SSTR];
    __shared__ float4 rxAS[2][18 * RSTR];
    __shared__ float4 rxBS[2][18 * RSTR];
    __shared__ float4 rxCS[2][INIT ? 18 * RSTR : 1];   // allocated only for INIT

    const float4 INF4  = make_float4(INFINITY, INFINITY, INFINITY, INFINITY);
    const float4 MINF4 = make_float4(-INFINITY, -INFINITY, -INFINITY, -INFINITY);
    const float4 ZERO4 = make_float4(0.f, 0.f, 0.f, 0.f);

    const int zlen  = ND / zchunks;
    const int v     = blockIdx.z / zchunks;
    const int chunk = blockIdx.z - v * zchunks;
    const int z0    = chunk * zlen;
    const int tx0   = blockIdx.x * TX;
    const int ty0   = blockIdx.y * TY;
    const int tid   = threadIdx.x;

    const float* src = srcB ? (v < 4 ? srcA + (size_t)v * NVOL_VOX
                                     : srcB + (size_t)(v - 4) * NVOL_VOX)
                            : srcA + (size_t)v * NVOL_VOX;
    const float4* src4 = (const float4*)src;
    float4* img4 = imgOut ? (float4*)(imgOut + (size_t)v * NVOL_VOX) : nullptr;
    float4* skl4 = (float4*)(skel + (size_t)v * NVOL_VOX);
    const float4* oth4 = nullptr;
    if (RED) {
        const float* oth = othB ? (v < 4 ? othA + (size_t)v * NVOL_VOX
                                         : othB + (size_t)(v - 4) * NVOL_VOX)
                                : othA + (size_t)v * NVOL_VOX;
        oth4 = (const float4*)oth;
    }

    const int fy = tid / 10, qx = tid - (tid / 10) * 10;   // rows 0..23
    const bool tOK = tid < 240;
    const bool aE1 = tOK && fy >= 1 && fy < 23;
    const bool aE2 = tOK && fy >= 2 && fy < 22;
    const bool aE3 = tOK && fy >= 3 && fy < 21;
    const bool aRx = aE3 && qx >= 1 && qx < 9;
    const bool aC  = tOK && fy >= 4 && fy < 20 && qx >= 1 && qx < 9;
    const int gy = ty0 + fy - 4;
    const int gx4 = tx0 + (qx - 1) * 4;
    const bool gOK = tOK && (unsigned)gy < NH && (unsigned)gx4 < NW;
    const int colBase = gOK ? ((gy * NW + gx4) >> 2) : 0;
    const int iSrc = fy * SSTR + qx + 1;
    const int iE1  = (fy - 1) * SSTR + qx + 1;
    const int iE2  = (fy - 2) * SSTR + qx + 1;
    const int iE3  = (fy - 3) * SSTR + qx + 1;
    const int iRx  = (fy - 3) * RSTR + (qx - 1);

    // guards at cols 0 and 11 (data cols 1..10)
    for (int l = tid; l < 2 * 24 * 2; l += THREADS)
        srcS[l & 1][(l >> 2) * SSTR + ((l >> 1) & 1) * 11] = INF4;
    for (int l = tid; l < 2 * 22 * 2; l += THREADS)
        e1S[l & 1][(l >> 2) * SSTR + ((l >> 1) & 1) * 11] = INF4;
    for (int l = tid; l < 2 * 20 * 2; l += THREADS)
        e2S[l & 1][(l >> 2) * SSTR + ((l >> 1) & 1) * 11] = INF4;
    for (int l = tid; l < 2 * 18 * 2; l += THREADS)
        e3S[l & 1][(l >> 2) * SSTR + ((l >> 1) & 1) * 11] = INF4;
    __syncthreads();

    constexpr int SD = INIT ? 6 : 3;
    float4 srcF[SD], e1F[6], e2F[6], e3F[2], rxAF[2], rxBF[2], mxyAF[3], mxyBF[3], dAF[2];
    float4 sklF[6], othF[6];
    float4 rxCF[2], mxyCF[3], d0F[3];
#pragma unroll
    for (int i = 0; i < SD; ++i) srcF[i] = INF4;
#pragma unroll
    for (int i = 0; i < 6; ++i) { e1F[i] = INF4; e2F[i] = INF4; sklF[i] = ZERO4; othF[i] = ZERO4; }
    e3F[0] = e3F[1] = INF4;
    rxAF[0] = rxAF[1] = MINF4;
    rxBF[0] = rxBF[1] = MINF4;
    rxCF[0] = rxCF[1] = MINF4;
    mxyAF[0] = mxyAF[1] = mxyAF[2] = MINF4;
    mxyBF[0] = mxyBF[1] = mxyBF[2] = MINF4;
    mxyCF[0] = mxyCF[1] = mxyCF[2] = MINF4;
    dAF[0] = dAF[1] = ZERO4;
    d0F[0] = d0F[1] = d0F[2] = ZERO4;

    float accS = 0.f, accSO = 0.f;
    const int NSTEP = zlen + 10;

    for (int sb = 0; sb < NSTEP; sb += 6) {
#pragma unroll
        for (int u = 0; u < 6; ++u) {
            if (sb + u >= NSTEP) break;            // uniform exit at exact step count
            const int zL = z0 - 4 + (sb + u);
            const int sl  = u & 1;
            const int slp = sl ^ 1;

            {   // L(zL)
                float4 vv = INF4;
                if ((unsigned)zL < ND && zL < z0 + zlen + 4 && gOK)
                    vv = src4[zL * ZS4 + colBase];
                srcF[u % SD] = vv;
                if (tOK) srcS[sl][iSrc] = vv;
            }
            if (!INIT) {   // prefetch skel/oth for OUT 3 steps ahead (z = zL-3)
                const int zp = zL - 3;
                const bool pOK = aC && zp >= z0 && zp < z0 + zlen;
                float4 sv = ZERO4;
                if (pOK) sv = skl4[zp * ZS4 + colBase];
                sklF[u] = sv;
                if (RED) {
                    float4 ov = ZERO4;
                    if (pOK) ov = oth4[zp * ZS4 + colBase];
                    othF[u] = ov;
                }
            }
            {   // E1(zL-1)  (x-halo via b32)
                const int z = zL - 1;
                float4 vv = INF4;
                if (aE1 && (unsigned)z < ND) {
                    const float4* S = srcS[slp];
                    const float* fS = (const float*)S;
                    float4 cc = INIT ? srcF[(u + 5) % 6] : srcF[(u + 2) % SD];
                    float4 zm = INIT ? f4min(srcF[(u + 4) % 6], srcF[u % 6])
                                     : f4min(srcF[(u + 1) % SD], srcF[u % SD]);
                    float4 xm = f4winmin_s(fS[4 * iSrc - 1], cc, fS[4 * iSrc + 4]);
                    vv = f4min(f4min(xm, S[iSrc - SSTR]),
                               f4min(S[iSrc + SSTR], zm));
                }
                e1F[u % 6] = vv;
                if (aE1) e1S[sl][iE1] = vv;
            }
            {   // E2(zL-2) — img output  (x-halo via b32)
                const int z = zL - 2;
                float4 vv = INF4;
                if (aE2) {
                    const float4* S = e1S[slp];
                    const float* fS = (const float*)S;
                    float4 xm = f4winmin_s(fS[4 * iE1 - 1], e1F[(u + 5) % 6], fS[4 * iE1 + 4]);
                    vv = f4min(f4min(xm, S[iE1 - SSTR]),
                               f4min(S[iE1 + SSTR],
                                     f4min(e1F[(u + 4) % 6], e1F[u % 6])));
                    e2S[sl][iE2] = vv;
                    if (img4 && aC && z >= z0 && z < z0 + zlen)
                        img4[z * ZS4 + colBase] = vv;
                }
                e2F[u % 6] = vv;
            }
            {   // E3(zL-3)  (x-halo via b32)
                float4 vv = INF4;
                if (aE3) {
                    const float4* S = e2S[slp];
                    const float* fS = (const float*)S;
                    float4 xm = f4winmin_s(fS[4 * iE2 - 1], e2F[(u + 5) % 6], fS[4 * iE2 + 4]);
                    vv = f4min(f4min(xm, S[iE2 - SSTR]),
                               f4min(S[iE2 + SSTR],
                                     f4min(e2F[(u + 4) % 6], e2F[u % 6])));
                    e3S[sl][iE3] = vv;
                }
                e3F[u % 2] = vv;
            }
            {   // rxA(zL-3), rxB(zL-4), [INIT] rxC(zL-2)  (x-halos via b32)
                float4 ra = MINF4, rb = MINF4, rc = MINF4;
                if (aRx) {
                    const float* fA = (const float*)e2S[slp];
                    const float* fB = (const float*)e3S[slp];
                    ra = f4winmax_s(fA[4 * iE2 - 1], e2F[(u + 5) % 6], fA[4 * iE2 + 4]);
                    rb = f4winmax_s(fB[4 * iE3 - 1], e3F[(u + 1) % 2], fB[4 * iE3 + 4]);
                    rxAS[sl][iRx] = ra;
                    rxBS[sl][iRx] = rb;
                    if (INIT) {
                        const float* fC = (const float*)e1S[slp];
                        rc = f4winmax_s(fC[4 * iE1 - 1], e1F[(u + 5) % 6], fC[4 * iE1 + 4]);
                        rxCS[sl][iRx] = rc;
                    }
                }
                float4 mA = MINF4, mB = MINF4, mC = MINF4;
                if (aC) {
                    mA = f4max(f4max(rxAF[(u + 1) % 2], rxAS[slp][iRx - RSTR]),
                               rxAS[slp][iRx + RSTR]);
                    mB = f4max(f4max(rxBF[(u + 1) % 2], rxBS[slp][iRx - RSTR]),
                               rxBS[slp][iRx + RSTR]);
                    if (INIT)
                        mC = f4max(f4max(rxCF[(u + 1) % 2], rxCS[slp][iRx - RSTR]),
                                   rxCS[slp][iRx + RSTR]);
                }
                rxAF[u % 2] = ra;
                rxBF[u % 2] = rb;
                mxyAF[u % 3] = mA;
                mxyBF[u % 3] = mB;
                if (INIT) { rxCF[u % 2] = rc; mxyCF[u % 3] = mC; }
            }
            if (INIT) {   // d0(zL-4) = relu(src(zL-4) - dilate(E1)(zL-4))
                float4 dilC = f4max(f4max(mxyCF[0], mxyCF[1]), mxyCF[2]);
                d0F[u % 3] = f4relu_sub(srcF[(u + 2) % 6], dilC);
            }
            {   // dA(zL-5) = relu(E1(zL-5) - dilA)
                float4 dilA = f4max(f4max(mxyAF[0], mxyAF[1]), mxyAF[2]);
                dAF[u % 2] = f4relu_sub(e1F[(u + 2) % 6], dilA);
            }
            {   // OUT(zL-6)
                const int z = zL - 6;
                if (aC && z >= z0 && z < z0 + zlen) {
                    float4 dilB = f4max(f4max(mxyBF[0], mxyBF[1]), mxyBF[2]);
                    float4 dB = f4relu_sub(e2F[(u + 2) % 6], dilB);
                    float4 da = dAF[(u + 1) % 2];
                    int gi = z * ZS4 + colBase;
                    float4 sv = INIT ? d0F[(u + 1) % 3] : sklF[(u + 3) % 6];
                    float4 s1, s2;
                    s1.x = sv.x + fmaxf(da.x - sv.x * da.x, 0.f);
                    s1.y = sv.y + fmaxf(da.y - sv.y * da.y, 0.f);
                    s1.z = sv.z + fmaxf(da.z - sv.z * da.z, 0.f);
                    s1.w = sv.w + fmaxf(da.w - sv.w * da.w, 0.f);
                    s2.x = s1.x + fmaxf(dB.x - s1.x * dB.x, 0.f);
                    s2.y = s1.y + fmaxf(dB.y - s1.y * dB.y, 0.f);
                    s2.z = s1.z + fmaxf(dB.z - s1.z * dB.z, 0.f);
                    s2.w = s1.w + fmaxf(dB.w - s1.w * dB.w, 0.f);
                    skl4[gi] = s2;
                    if (RED) {
                        accS += s2.x + s2.y + s2.z + s2.w;
                        float4 o = othF[(u + 3) % 6];
                        accSO += s2.x * o.x + s2.y * o.y + s2.z * o.z + s2.w * o.w;
                    }
                }
            }
            __syncthreads();
        }
    }

    if (RED) {
        float* sbuf = (float*)srcS;
        float r1 = block_reduce(accS, sbuf);
        float r2 = block_reduce(accSO, sbuf);
        if (tid == 0) {
            int halfSel = (othB && v >= 4) ? 1 : 0;
            int A = (offBase + 2 * halfSel) * 1024;
            int zslot = chunk + zchunks * (v & 3);
            int bid = blockIdx.x + 4 * (blockIdx.y + 8 * zslot);
            part[A + bid] = r1;
            part[A + 1024 + bid] = r2;
        }
    }
}

// ---------------------------------------------------------------------------
// finalize: sum 7 partial arrays (1024 each) and compute the loss scalar
// ---------------------------------------------------------------------------
__global__ void finalize_kernel(const float* __restrict__ part, float* __restrict__ out) {
    __shared__ float sbuf[THREADS / 64];
    float s[7];
#pragma unroll
    for (int k = 0; k < 7; ++k) {
        float local = 0.f;
        for (int i = threadIdx.x; i < 1024; i += THREADS) local += part[k * 1024 + i];
        s[k] = block_reduce(local, sbuf);
    }
    if (threadIdx.x == 0) {
        const float smooth = 1.0f;
        const float alpha = 0.3f;
        float dice = 1.f - (2.f * s[2] + smooth) / (s[1] + s[0] + smooth);
        float tprec = (s[4] + smooth) / (s[3] + smooth);
        float tsens = (s[6] + smooth) / (s[5] + smooth);
        float cl = 1.f - 2.f * (tprec * tsens) / (tprec + tsens);
        out[0] = (1.f - alpha) * dice + alpha * cl;
    }
}

// ---------------------------------------------------------------------------
extern "C" void kernel_launch(void* const* d_in, const int* in_sizes, int n_in,
                              void* d_out, int out_size, void* d_ws, size_t ws_size,
                              hipStream_t stream) {
    const float* y_pred = (const float*)d_in[0];
    const float* y_true = (const float*)d_in[1];
    float* out = (float*)d_out;

    char* ws = (char*)d_ws;
    float* part = (float*)ws;                 // 7 * 1024 floats
    float* yp = (float*)(ws + 32768);
    const size_t NB4 = (size_t)NVOX;
    const size_t need_batched = 32768 + 7 * NB4 * sizeof(float);

    hipMemsetAsync(part, 0, 7 * 1024 * sizeof(float), stream);
    sigmoid_reduce_kernel<<<SIG_BLOCKS, THREADS, 0, stream>>>(
        (const float4*)y_pred, (const float4*)y_true, (float4*)yp, part);

    if (ws_size >= need_batched) {
        // batched: both skeletons (8 volumes) per dispatch
        float* ping = yp + NB4;          // 8-vol
        float* pong = ping + 2 * NB4;    // 8-vol
        float* S    = pong + 2 * NB4;    // 8-vol
        const int zc = 2;                // zlen 64 -> 512 blocks, fully co-resident
        dim3 grid(NW / TX, NH / TY, zc * 8);   // 4 x 8 x 16 = 512

        // init + iters 1-2 fused; img out = E2
        skel_pair_kernel<0, 1><<<grid, THREADS, 0, stream>>>(
            yp, y_true, ping, S, zc, nullptr, nullptr, nullptr, 0);

        float* bufs[2] = {ping, pong};
        for (int j = 0; j < 7; ++j) {         // iters 3-16 (7 pairs)
            const float* sA = bufs[j & 1];
            float* oimg = (j < 6) ? bufs[(j + 1) & 1] : nullptr;
            if (j < 6)
                skel_pair_kernel<0, 0><<<grid, THREADS, 0, stream>>>(
                    sA, nullptr, oimg, S, zc, nullptr, nullptr, nullptr, 0);
            else
                skel_pair_kernel<1, 0><<<grid, THREADS, 0, stream>>>(
                    sA, nullptr, oimg, S, zc, y_true, yp, part, 3);
        }
    } else {
        // sequential fallback: one skeleton stream (4 vols) at a time
        float* ping = yp + NB4;
        float* pong = ping + NB4;
        float* Sp   = pong + NB4;
        float* St   = Sp + NB4;
        const int zc = 4;                // zlen 32 -> 512 blocks
        dim3 grid(NW / TX, NH / TY, zc * 4);

        auto run = [&](const float* x, float* S, const float* other, int offBase) {
            skel_pair_kernel<0, 1><<<grid, THREADS, 0, stream>>>(
                x, nullptr, ping, S, zc, nullptr, nullptr, nullptr, 0);
            float* bufs[2] = {ping, pong};
            for (int j = 0; j < 7; ++j) {
                const float* sA = bufs[j & 1];
                float* oimg = (j < 6) ? bufs[(j + 1) & 1] : nullptr;
                if (j < 6)
                    skel_pair_kernel<0, 0><<<grid, THREADS, 0, stream>>>(
                        sA, nullptr, oimg, S, zc, nullptr, nullptr, nullptr, 0);
                else
                    skel_pair_kernel<1, 0><<<grid, THREADS, 0, stream>>>(
                        sA, nullptr, oimg, S, zc, other, nullptr, part, offBase);
            }
        };
        run(yp, Sp, y_true, 3);
        run(y_true, St, yp, 5);
    }

    finalize_kernel<<<1, THREADS, 0, stream>>>(part, out);
}